// Round 9
// baseline (602.098 us; speedup 1.0000x reference)
//
#include <hip/hip_runtime.h>

// Self-attention B=2, S=4096, D=1024, fp32 in/out.
//
// Round-9: coalesced mask epilogue for the 256^2 scores kernel.
//   Round-8 counters: FETCH 128 MB/dispatch (ideal staging 33.6 MB) -- the
//   fp32 mask is read TRANSPOSED in the epilogue (lane-stride 16 KB -> 64
//   transactions per instr, ~8192 VMEM transactions/wave ~= 25-30 us/block
//   at 1 block/CU). Fix: transpose mask once into maskT[q][k] bf16 with the
//   ==0 -> -inf fill pre-encoded (0xFF80); epilogue reads become contiguous.
//   Fallback to the round-8 path if ws_size can't fit maskT (+33.5 MB).
//
// Engine/algebra unchanged from round 8:
//   * QM trick: scores = (E*M)*E^T, Mt = Wq*Wk^T (original-layout weights).
//   * Split-bf16 {hh,hl,lh} fp32 emulation; XOR-swizzled LDS (conflicts=0).
//   * scores: 8-wave 256^2 4-phase dbuf kernel; rest: 128^2 m97 engine.

#define S_LEN 4096

typedef __bf16 bf16x8 __attribute__((ext_vector_type(8)));
typedef float f32x4 __attribute__((ext_vector_type(4)));

__device__ __forceinline__ unsigned short f2bf(float x) {
  unsigned u = __float_as_uint(x);
  unsigned r = u + 0x7fffu + ((u >> 16) & 1u);  // round-to-nearest-even
  return (unsigned short)(r >> 16);
}
__device__ __forceinline__ float bf2f(unsigned short h) {
  return __uint_as_float(((unsigned)h) << 16);
}

__device__ __forceinline__ void gl_lds16(const void* g, void* l) {
  __builtin_amdgcn_global_load_lds(
      (const __attribute__((address_space(1))) void*)g,
      (__attribute__((address_space(3))) void*)l, 16, 0, 0);
}

// ---------------------------------------------------------------------------
// split32: fp32 -> (hi, lo) bf16 pair, elementwise, float4-vectorized.
__launch_bounds__(256)
__global__ void split32(const float* __restrict__ e,
                        unsigned short* __restrict__ Eh,
                        unsigned short* __restrict__ El) {
  int i = blockIdx.x * 256 + threadIdx.x;  // float4 index
  float4 v = reinterpret_cast<const float4*>(e)[i];
  ushort4 h, l;
  h.x = f2bf(v.x); l.x = f2bf(v.x - bf2f(h.x));
  h.y = f2bf(v.y); l.y = f2bf(v.y - bf2f(h.y));
  h.z = f2bf(v.z); l.z = f2bf(v.z - bf2f(h.z));
  h.w = f2bf(v.w); l.w = f2bf(v.w - bf2f(h.w));
  reinterpret_cast<ushort4*>(Eh)[i] = h;
  reinterpret_cast<ushort4*>(El)[i] = l;
}

// ---------------------------------------------------------------------------
// prep_wv: Wv[d][e] -> Wvt[e][d] plain bf16. 32x32 LDS transpose.
__launch_bounds__(256)
__global__ void prep_wv(const float* __restrict__ wv, unsigned short* __restrict__ Wvt) {
  __shared__ float tile[32][33];
  const int bx = blockIdx.x * 32;
  const int by = blockIdx.y * 32;
  const int tx = threadIdx.x;
  const int ty = threadIdx.y;
#pragma unroll
  for (int j = 0; j < 4; ++j)
    tile[ty + j * 8][tx] = wv[(long)(by + ty + j * 8) * 1024 + bx + tx];
  __syncthreads();
#pragma unroll
  for (int j = 0; j < 4; ++j) {
    float v = tile[tx][ty + j * 8];
    Wvt[(long)(bx + ty + j * 8) * 1024 + by + tx] = f2bf(v);
  }
}

// ---------------------------------------------------------------------------
// prep_maskT: maskT[q][k] = bf16(mask_filled[k][q]), with mask==0 -> -inf
// (0xFF80) pre-encoded. 32x32 LDS transpose, coalesced both sides.
__launch_bounds__(256)
__global__ void prep_maskT(const float* __restrict__ mask,
                           unsigned short* __restrict__ maskT) {
  __shared__ float tile[32][33];
  const int bx = blockIdx.x * 32;  // q block
  const int by = blockIdx.y * 32;  // k block
  const int tx = threadIdx.x;
  const int ty = threadIdx.y;
#pragma unroll
  for (int j = 0; j < 4; ++j)
    tile[ty + j * 8][tx] = mask[(long)(by + ty + j * 8) * S_LEN + bx + tx];
  __syncthreads();
#pragma unroll
  for (int j = 0; j < 4; ++j) {
    float v = tile[tx][ty + j * 8];  // = mask[by+tx][bx+ty+j*8]
    unsigned short u = (v == 0.0f) ? (unsigned short)0xFF80 : f2bf(v);
    maskT[(long)(bx + ty + j * 8) * S_LEN + by + tx] = u;
  }
}

// ---------------------------------------------------------------------------
// Round-7 128^2 engine (proven): NT GEMM with XOR-swizzled LDS.
// MODE 0: hi/lo pair store  MODE 2: bf16 store  MODE 3: f32 store.
template <int SPLIT, int MODE>
__launch_bounds__(256)
__global__ void gemm_bt(const unsigned short* __restrict__ Ah,
                        const unsigned short* __restrict__ Al, int lda,
                        const unsigned short* __restrict__ Bh,
                        const unsigned short* __restrict__ Bl, int ldb,
                        void* __restrict__ Cp, int ldc,
                        unsigned short* __restrict__ C2, int kIters) {
  __shared__ unsigned short lAh[128 * 32];
  __shared__ unsigned short lBh[128 * 32];
  __shared__ unsigned short lAl[SPLIT ? 128 * 32 : 8];
  __shared__ unsigned short lBl[SPLIT ? 128 * 32 : 8];

  const int t = threadIdx.x;
  const int w = t >> 6;
  const int lane = t & 63;
  const int g = lane >> 4;
  const int r = lane & 15;
  const int wm = (w >> 1) * 64;
  const int wn = (w & 1) * 64;
  const long bm = (long)blockIdx.x * 128;
  const long bn = (long)blockIdx.y * 128;

  f32x4 acc[4][4];
  const f32x4 vzero = {0.f, 0.f, 0.f, 0.f};
#pragma unroll
  for (int mi = 0; mi < 4; ++mi)
#pragma unroll
    for (int ni = 0; ni < 4; ++ni) acc[mi][ni] = vzero;

  for (int kt = 0; kt < kIters; ++kt) {
    __syncthreads();
    const long kbase = (long)kt * 32;
#pragma unroll
    for (int i = 0; i < 2; ++i) {
      int s = (i * 4 + w) * 64 + lane;
      int row = s >> 2;
      int ko = (s & 3) ^ ((row >> 1) & 3);
      long goffA = (bm + row) * (long)lda + kbase + ko * 8;
      long goffB = (bn + row) * (long)ldb + kbase + ko * 8;
      int lbase = (i * 4 + w) * 512;
      gl_lds16(Ah + goffA, lAh + lbase);
      gl_lds16(Bh + goffB, lBh + lbase);
      if constexpr (SPLIT) {
        gl_lds16(Al + goffA, lAl + lbase);
        gl_lds16(Bl + goffB, lBl + lbase);
      }
    }
    __syncthreads();

    bf16x8 af[4], bfh[4], af2[4], bf2v[4];
#pragma unroll
    for (int mi = 0; mi < 4; ++mi) {
      int rowa = wm + mi * 16 + r;
      int o = rowa * 32 + ((g ^ ((rowa >> 1) & 3)) * 8);
      af[mi] = *reinterpret_cast<const bf16x8*>(&lAh[o]);
      if constexpr (SPLIT)
        af2[mi] = *reinterpret_cast<const bf16x8*>(&lAl[o]);
    }
#pragma unroll
    for (int ni = 0; ni < 4; ++ni) {
      int rowb = wn + ni * 16 + r;
      int o = rowb * 32 + ((g ^ ((rowb >> 1) & 3)) * 8);
      bfh[ni] = *reinterpret_cast<const bf16x8*>(&lBh[o]);
      if constexpr (SPLIT)
        bf2v[ni] = *reinterpret_cast<const bf16x8*>(&lBl[o]);
    }
#pragma unroll
    for (int mi = 0; mi < 4; ++mi)
#pragma unroll
      for (int ni = 0; ni < 4; ++ni) {
        acc[mi][ni] = __builtin_amdgcn_mfma_f32_16x16x32_bf16(af[mi], bfh[ni], acc[mi][ni], 0, 0, 0);
        if constexpr (SPLIT) {
          acc[mi][ni] = __builtin_amdgcn_mfma_f32_16x16x32_bf16(af[mi], bf2v[ni], acc[mi][ni], 0, 0, 0);
          acc[mi][ni] = __builtin_amdgcn_mfma_f32_16x16x32_bf16(af2[mi], bfh[ni], acc[mi][ni], 0, 0, 0);
        }
      }
  }

#pragma unroll
  for (int mi = 0; mi < 4; ++mi) {
#pragma unroll
    for (int ni = 0; ni < 4; ++ni) {
      long row0 = bm + wm + mi * 16 + g * 4;
      long col = bn + wn + ni * 16 + r;
#pragma unroll
      for (int q = 0; q < 4; ++q) {
        float v = acc[mi][ni][q];
        long row = row0 + q;
        if constexpr (MODE == 0) {
          unsigned short h = f2bf(v);
          ((unsigned short*)Cp)[row * (long)ldc + col] = h;
          C2[row * (long)ldc + col] = f2bf(v - bf2f(h));
        } else if constexpr (MODE == 2) {
          ((unsigned short*)Cp)[row * (long)ldc + col] = f2bf(v);
        } else {
          ((float*)Cp)[row * (long)ldc + col] = v;
        }
      }
    }
  }
}

// ---------------------------------------------------------------------------
// 256^2 8-wave deep-pipelined SPLIT NT GEMM, scores epilogue.
// C[m][n] = (sum_k A[m][k]*B[n][k]) * scale + mask_filled^T, fp32 store.
// maskT (bf16, -inf pre-encoded) if available, else transposed fp32 mask.
__launch_bounds__(512, 2)
__global__ void gemm8s(const unsigned short* __restrict__ Ah,
                       const unsigned short* __restrict__ Al, int lda,
                       const unsigned short* __restrict__ Bh,
                       const unsigned short* __restrict__ Bl, int ldb,
                       float* __restrict__ C, int ldc,
                       const float* __restrict__ mask,
                       const unsigned short* __restrict__ maskT,
                       float scale, int nkt) {
  __shared__ __align__(16) unsigned short lds[4][2][8192];

  const int t = threadIdx.x;          // 0..511
  const int w = t >> 6;               // wave 0..7
  const int lane = t & 63;
  const int g = lane >> 4;
  const int r = lane & 15;
  const int wr = w >> 2;              // 0..1  (M)
  const int wc = w & 3;               // 0..3  (N)
  const long bm = (long)blockIdx.x * 256;
  const long bn = (long)blockIdx.y * 256;

  const int row0 = t >> 2;
  const int ko = (t & 3) ^ ((t >> 3) & 3);
  const unsigned short* pAh = Ah + (bm + row0) * (long)lda + ko * 8;
  const unsigned short* pAl = Al + (bm + row0) * (long)lda + ko * 8;
  const unsigned short* pBh = Bh + (bn + row0) * (long)ldb + ko * 8;
  const unsigned short* pBl = Bl + (bn + row0) * (long)ldb + ko * 8;

  f32x4 acc[8][4];
  const f32x4 vzero = {0.f, 0.f, 0.f, 0.f};
#pragma unroll
  for (int mi = 0; mi < 8; ++mi)
#pragma unroll
    for (int ni = 0; ni < 4; ++ni) acc[mi][ni] = vzero;

  // Prologue: stage K-step 0 into buf 0.
#pragma unroll
  for (int T = 0; T < 4; ++T) {
    const unsigned short* sp = (T == 0) ? pAh : (T == 1) ? pAl : (T == 2) ? pBh : pBl;
    long ld = (T < 2) ? lda : ldb;
    gl_lds16(sp, &lds[T][0][w * 512]);
    gl_lds16(sp + 128 * ld, &lds[T][0][4096 + w * 512]);
  }
  asm volatile("s_waitcnt vmcnt(0)" ::: "memory");
  __syncthreads();

  for (int kt = 0; kt < nkt; ++kt) {
    const int cb = kt & 1, nb = cb ^ 1;
    const bool stg = (kt < nkt - 1);
    bf16x8 bh[4], bl[4];
#pragma unroll
    for (int p = 0; p < 4; ++p) {
      if (p == 0) {
#pragma unroll
        for (int ni = 0; ni < 4; ++ni) {
          int rowb = wc * 64 + ni * 16 + r;
          int o = rowb * 32 + ((g ^ ((rowb >> 1) & 3)) * 8);
          bh[ni] = *reinterpret_cast<const bf16x8*>(&lds[2][cb][o]);
          bl[ni] = *reinterpret_cast<const bf16x8*>(&lds[3][cb][o]);
        }
      }
      bf16x8 ah[2], al[2];
#pragma unroll
      for (int i = 0; i < 2; ++i) {
        int rowa = wr * 128 + (2 * p + i) * 16 + r;
        int o = rowa * 32 + ((g ^ ((rowa >> 1) & 3)) * 8);
        ah[i] = *reinterpret_cast<const bf16x8*>(&lds[0][cb][o]);
        al[i] = *reinterpret_cast<const bf16x8*>(&lds[1][cb][o]);
      }
      if (stg && p == 0) {
        gl_lds16(pAh + 32, &lds[0][nb][w * 512]);
        gl_lds16(pAh + 32 + 128 * (long)lda, &lds[0][nb][4096 + w * 512]);
        gl_lds16(pAl + 32, &lds[1][nb][w * 512]);
        gl_lds16(pAl + 32 + 128 * (long)lda, &lds[1][nb][4096 + w * 512]);
      }
      if (stg && p == 1) {
        gl_lds16(pBh + 32, &lds[2][nb][w * 512]);
        gl_lds16(pBh + 32 + 128 * (long)ldb, &lds[2][nb][4096 + w * 512]);
        gl_lds16(pBl + 32, &lds[3][nb][w * 512]);
        gl_lds16(pBl + 32 + 128 * (long)ldb, &lds[3][nb][4096 + w * 512]);
      }
      __builtin_amdgcn_s_barrier();
      __builtin_amdgcn_s_setprio(1);
#pragma unroll
      for (int i = 0; i < 2; ++i) {
        const int mi = 2 * p + i;
#pragma unroll
        for (int ni = 0; ni < 4; ++ni) {
          acc[mi][ni] = __builtin_amdgcn_mfma_f32_16x16x32_bf16(ah[i], bh[ni], acc[mi][ni], 0, 0, 0);
          acc[mi][ni] = __builtin_amdgcn_mfma_f32_16x16x32_bf16(ah[i], bl[ni], acc[mi][ni], 0, 0, 0);
          acc[mi][ni] = __builtin_amdgcn_mfma_f32_16x16x32_bf16(al[i], bh[ni], acc[mi][ni], 0, 0, 0);
        }
      }
      __builtin_amdgcn_s_setprio(0);
      if (p < 3) __builtin_amdgcn_s_barrier();
    }
    asm volatile("s_waitcnt vmcnt(0)" ::: "memory");
    __syncthreads();
    pAh += 32; pAl += 32; pBh += 32; pBl += 32;
  }

  // Epilogue: scores = acc*scale + mask_filled^T.
  if (maskT) {
    // coalesced bf16 maskT[row][col] (-inf pre-encoded; v*scale + -inf = -inf)
#pragma unroll
    for (int mi = 0; mi < 8; ++mi) {
#pragma unroll
      for (int ni = 0; ni < 4; ++ni) {
        long row0q = bm + wr * 128 + mi * 16 + g * 4;
        long col = bn + wc * 64 + ni * 16 + r;
#pragma unroll
        for (int q = 0; q < 4; ++q) {
          long row = row0q + q;
          float mv = bf2f(maskT[row * (long)S_LEN + col]);
          C[row * (long)ldc + col] = acc[mi][ni][q] * scale + mv;
        }
      }
    }
  } else {
    // fallback: transposed fp32 mask (round-8 path)
#pragma unroll
    for (int mi = 0; mi < 8; ++mi) {
#pragma unroll
      for (int ni = 0; ni < 4; ++ni) {
        long row0q = bm + wr * 128 + mi * 16 + g * 4;
        long col = bn + wc * 64 + ni * 16 + r;
#pragma unroll
        for (int q = 0; q < 4; ++q) {
          long row = row0q + q;
          float mv = mask[col * (long)S_LEN + row];
          float v = acc[mi][ni][q] * scale;
          v = (mv == 0.0f) ? -__builtin_inff() : (v + mv);
          C[row * (long)ldc + col] = v;
        }
      }
    }
  }
}

// ---------------------------------------------------------------------------
// Row softmax, IN PLACE: fp32 row -> bf16 P in the same storage.
__launch_bounds__(256)
__global__ void softmax_rows(float* __restrict__ Sc) {
  const long row = blockIdx.x;
  float* sr = Sc + row * (long)S_LEN;
  unsigned short* pr = (unsigned short*)sr;
  const int t = threadIdx.x;
  const int lane = t & 63, wid = t >> 6;

  float4 x[4];
  float m = -3.0e38f;
#pragma unroll
  for (int i = 0; i < 4; ++i) {
    x[i] = reinterpret_cast<const float4*>(sr)[t + i * 256];
    m = fmaxf(m, fmaxf(fmaxf(x[i].x, x[i].y), fmaxf(x[i].z, x[i].w)));
  }
#pragma unroll
  for (int o = 32; o; o >>= 1) m = fmaxf(m, __shfl_xor(m, o));
  __shared__ float redm[4];
  __shared__ float reds[4];
  if (lane == 0) redm[wid] = m;
  __syncthreads();
  m = fmaxf(fmaxf(redm[0], redm[1]), fmaxf(redm[2], redm[3]));

  float e[16];
  float s = 0.f;
#pragma unroll
  for (int i = 0; i < 4; ++i) {
    e[i * 4 + 0] = __expf(x[i].x - m);
    e[i * 4 + 1] = __expf(x[i].y - m);
    e[i * 4 + 2] = __expf(x[i].z - m);
    e[i * 4 + 3] = __expf(x[i].w - m);
    s += e[i * 4 + 0] + e[i * 4 + 1] + e[i * 4 + 2] + e[i * 4 + 3];
  }
#pragma unroll
  for (int o = 32; o; o >>= 1) s += __shfl_xor(s, o);
  if (lane == 0) reds[wid] = s;
  __syncthreads();
  s = reds[0] + reds[1] + reds[2] + reds[3];
  float inv = 1.0f / s;
#pragma unroll
  for (int i = 0; i < 4; ++i) {
    ushort4 o4;
    o4.x = f2bf(e[i * 4 + 0] * inv);
    o4.y = f2bf(e[i * 4 + 1] * inv);
    o4.z = f2bf(e[i * 4 + 2] * inv);
    o4.w = f2bf(e[i * 4 + 3] * inv);
    reinterpret_cast<ushort4*>(pr)[t + i * 256] = o4;
  }
}

// ---------------------------------------------------------------------------
extern "C" void kernel_launch(void* const* d_in, const int* in_sizes, int n_in,
                              void* d_out, int out_size, void* d_ws, size_t ws_size,
                              hipStream_t stream) {
  const float* emb  = (const float*)d_in[0];
  const float* mask = (const float*)d_in[1];
  const float* wq   = (const float*)d_in[2];
  const float* wk   = (const float*)d_in[3];
  const float* wv   = (const float*)d_in[4];
  float* out = (float*)d_out;
  char* ws = (char*)d_ws;

  // Workspace layout (bytes): rounds 4-8 layout (106,954,752, proven) plus
  // optional maskT [4096][4096] bf16 at 106,954,752 (need2 = 140,509,184).
  const size_t need = 106954752;
  const size_t need2 = need + (size_t)S_LEN * S_LEN * 2;
  if (ws_size < need) return;
  const bool useT = (ws_size >= need2);

  unsigned short* Eh  = (unsigned short*)(ws);
  unsigned short* El  = (unsigned short*)(ws + 8388608);
  unsigned short* QMh = (unsigned short*)(ws + 16777216);
  unsigned short* QMl = (unsigned short*)(ws + 25165824);
  unsigned short* Vt  = QMh;  // alias, live only after scores
  unsigned short* MtH = (unsigned short*)(ws + 33554432);
  unsigned short* MtL = (unsigned short*)(ws + 35651584);
  unsigned short* Wvt = (unsigned short*)(ws + 37748736);
  float* scores       = (float*)(ws + 39845888);
  unsigned short* WqH = (unsigned short*)(ws + 39845888);
  unsigned short* WqL = (unsigned short*)(ws + 39845888 + 2097152);
  unsigned short* WkH = (unsigned short*)(ws + 39845888 + 4194304);
  unsigned short* WkL = (unsigned short*)(ws + 39845888 + 6291456);
  unsigned short* maskT = useT ? (unsigned short*)(ws + need) : nullptr;

  // ---- once: split weights, transpose Wv (+mask), precompute Mt -----------
  split32<<<1024, 256, 0, stream>>>(wq, WqH, WqL);
  split32<<<1024, 256, 0, stream>>>(wk, WkH, WkL);
  prep_wv<<<dim3(32, 32), dim3(32, 8), 0, stream>>>(wv, Wvt);
  if (useT)
    prep_maskT<<<dim3(128, 128), dim3(32, 8), 0, stream>>>(mask, maskT);
  gemm_bt<1, 0><<<dim3(8, 8), 256, 0, stream>>>(
      WkH, WkL, 1024, WqH, WqL, 1024, (void*)MtH, 1024, MtL, 32);

  for (int b = 0; b < 2; ++b) {
    const float* embb = emb + (size_t)b * 4096 * 1024;
    float* outb = out + (size_t)b * 4096 * 1024;

    // 1) split embeddings into bf16 hi/lo
    split32<<<4096, 256, 0, stream>>>(embb, Eh, El);
    // 2) QM = E*Mt^T (SPLIT, 128^2 engine), hi/lo store
    gemm_bt<1, 0><<<dim3(32, 8), 256, 0, stream>>>(
        Eh, El, 1024, MtH, MtL, 1024, (void*)QMh, 1024, QMl, 32);
    // 3) scores = (QM * E^T)/32 + mask_filled^T  (256^2 8-wave engine)
    gemm8s<<<dim3(16, 16), 512, 0, stream>>>(
        QMh, QMl, 1024, Eh, El, 1024, scores, 4096, mask, maskT, 0.03125f, 32);
    // 4) Vt = Wvt * E^T (plain bf16; overwrites dead QMh region)
    gemm_bt<0, 2><<<dim3(8, 32), 256, 0, stream>>>(
        Wvt, nullptr, 1024, Eh, nullptr, 1024, (void*)Vt, 4096, nullptr, 32);
    // 5) row softmax -> P bf16, in place (row stride 8192 ushorts)
    softmax_rows<<<4096, 256, 0, stream>>>(scores);
    // 6) out = P @ V (plain, 128^2 engine), fp32 store
    gemm_bt<0, 3><<<dim3(32, 8), 256, 0, stream>>>(
        (unsigned short*)scores, nullptr, 8192, Vt, nullptr, 4096,
        (void*)outb, 1024, nullptr, 128);
  }
}

// Round 10
// 601.116 us; speedup vs baseline: 1.0016x; 1.0016x over previous
//
#include <hip/hip_runtime.h>

// Self-attention B=2, S=4096, D=1024, fp32 in/out.
//
// Round-10: T4 counted-vmcnt for the scores kernel.
//   * gemm8s: BM=256 x BN=128, BK=32, 8 waves (4M x 2N, 64x64/wave),
//     THREE LDS stages (48KB each = 144KB) -> counted s_waitcnt vmcnt(6)
//     at K-step start (own buffer complete, next step's 6 loads stay in
//     flight). No vmcnt(0) drain in the main loop (T3+T4). setprio around
//     MFMA clusters (T5). XOR-swizzled LDS (conflicts=0, round-7-proven),
//     bf16 maskT epilogue (round-9-proven).
//   * gemm_bt gains KU (K-unroll): PV/Vt run BK=64 (two 32-wide subtiles
//     per barrier pair -> half the per-step drains). SPLIT kernels stay
//     BK=32 (LDS/occupancy, m132).
// Algebra unchanged: QM trick + split-bf16 {hh,hl,lh} fp32 emulation.

#define S_LEN 4096

typedef __bf16 bf16x8 __attribute__((ext_vector_type(8)));
typedef float f32x4 __attribute__((ext_vector_type(4)));

__device__ __forceinline__ unsigned short f2bf(float x) {
  unsigned u = __float_as_uint(x);
  unsigned r = u + 0x7fffu + ((u >> 16) & 1u);  // round-to-nearest-even
  return (unsigned short)(r >> 16);
}
__device__ __forceinline__ float bf2f(unsigned short h) {
  return __uint_as_float(((unsigned)h) << 16);
}

__device__ __forceinline__ void gl_lds16(const void* g, void* l) {
  __builtin_amdgcn_global_load_lds(
      (const __attribute__((address_space(1))) void*)g,
      (__attribute__((address_space(3))) void*)l, 16, 0, 0);
}

// ---------------------------------------------------------------------------
// split32: fp32 -> (hi, lo) bf16 pair, elementwise, float4-vectorized.
__launch_bounds__(256)
__global__ void split32(const float* __restrict__ e,
                        unsigned short* __restrict__ Eh,
                        unsigned short* __restrict__ El) {
  int i = blockIdx.x * 256 + threadIdx.x;  // float4 index
  float4 v = reinterpret_cast<const float4*>(e)[i];
  ushort4 h, l;
  h.x = f2bf(v.x); l.x = f2bf(v.x - bf2f(h.x));
  h.y = f2bf(v.y); l.y = f2bf(v.y - bf2f(h.y));
  h.z = f2bf(v.z); l.z = f2bf(v.z - bf2f(h.z));
  h.w = f2bf(v.w); l.w = f2bf(v.w - bf2f(h.w));
  reinterpret_cast<ushort4*>(Eh)[i] = h;
  reinterpret_cast<ushort4*>(El)[i] = l;
}

// ---------------------------------------------------------------------------
// prep_wv: Wv[d][e] -> Wvt[e][d] plain bf16. 32x32 LDS transpose.
__launch_bounds__(256)
__global__ void prep_wv(const float* __restrict__ wv, unsigned short* __restrict__ Wvt) {
  __shared__ float tile[32][33];
  const int bx = blockIdx.x * 32;
  const int by = blockIdx.y * 32;
  const int tx = threadIdx.x;
  const int ty = threadIdx.y;
#pragma unroll
  for (int j = 0; j < 4; ++j)
    tile[ty + j * 8][tx] = wv[(long)(by + ty + j * 8) * 1024 + bx + tx];
  __syncthreads();
#pragma unroll
  for (int j = 0; j < 4; ++j) {
    float v = tile[tx][ty + j * 8];
    Wvt[(long)(bx + ty + j * 8) * 1024 + by + tx] = f2bf(v);
  }
}

// ---------------------------------------------------------------------------
// prep_maskT: maskT[q][k] = bf16(mask_filled[k][q]), mask==0 -> -inf (0xFF80).
__launch_bounds__(256)
__global__ void prep_maskT(const float* __restrict__ mask,
                           unsigned short* __restrict__ maskT) {
  __shared__ float tile[32][33];
  const int bx = blockIdx.x * 32;  // q block
  const int by = blockIdx.y * 32;  // k block
  const int tx = threadIdx.x;
  const int ty = threadIdx.y;
#pragma unroll
  for (int j = 0; j < 4; ++j)
    tile[ty + j * 8][tx] = mask[(long)(by + ty + j * 8) * S_LEN + bx + tx];
  __syncthreads();
#pragma unroll
  for (int j = 0; j < 4; ++j) {
    float v = tile[tx][ty + j * 8];  // = mask[by+tx][bx+ty+j*8]
    unsigned short u = (v == 0.0f) ? (unsigned short)0xFF80 : f2bf(v);
    maskT[(long)(bx + ty + j * 8) * S_LEN + by + tx] = u;
  }
}

// ---------------------------------------------------------------------------
// 128^2 engine: NT GEMM with XOR-swizzled LDS. KU = K-unroll (subtiles of 32
// per barrier pair). MODE 0: hi/lo pair store  MODE 2: bf16  MODE 3: f32.
template <int SPLIT, int MODE, int KU>
__launch_bounds__(256)
__global__ void gemm_bt(const unsigned short* __restrict__ Ah,
                        const unsigned short* __restrict__ Al, int lda,
                        const unsigned short* __restrict__ Bh,
                        const unsigned short* __restrict__ Bl, int ldb,
                        void* __restrict__ Cp, int ldc,
                        unsigned short* __restrict__ C2, int kIters) {
  __shared__ unsigned short lAh[KU * 128 * 32];
  __shared__ unsigned short lBh[KU * 128 * 32];
  __shared__ unsigned short lAl[SPLIT ? 128 * 32 : 8];
  __shared__ unsigned short lBl[SPLIT ? 128 * 32 : 8];

  const int t = threadIdx.x;
  const int w = t >> 6;
  const int lane = t & 63;
  const int g = lane >> 4;
  const int r = lane & 15;
  const int wm = (w >> 1) * 64;
  const int wn = (w & 1) * 64;
  const long bm = (long)blockIdx.x * 128;
  const long bn = (long)blockIdx.y * 128;

  f32x4 acc[4][4];
  const f32x4 vzero = {0.f, 0.f, 0.f, 0.f};
#pragma unroll
  for (int mi = 0; mi < 4; ++mi)
#pragma unroll
    for (int ni = 0; ni < 4; ++ni) acc[mi][ni] = vzero;

  const int outer = kIters / KU;
  for (int kt = 0; kt < outer; ++kt) {
    __syncthreads();
    const long kbase = (long)kt * 32 * KU;
#pragma unroll
    for (int u = 0; u < KU; ++u) {
#pragma unroll
      for (int i = 0; i < 2; ++i) {
        int s = (i * 4 + w) * 64 + lane;
        int row = s >> 2;
        int ko = (s & 3) ^ ((row >> 1) & 3);
        long goffA = (bm + row) * (long)lda + kbase + u * 32 + ko * 8;
        long goffB = (bn + row) * (long)ldb + kbase + u * 32 + ko * 8;
        int lbase = u * 4096 + (i * 4 + w) * 512;
        gl_lds16(Ah + goffA, lAh + lbase);
        gl_lds16(Bh + goffB, lBh + lbase);
        if constexpr (SPLIT) {
          gl_lds16(Al + goffA, lAl + lbase);
          gl_lds16(Bl + goffB, lBl + lbase);
        }
      }
    }
    __syncthreads();

#pragma unroll
    for (int u = 0; u < KU; ++u) {
      bf16x8 af[4], bfh[4], af2[4], bf2v[4];
#pragma unroll
      for (int mi = 0; mi < 4; ++mi) {
        int rowa = wm + mi * 16 + r;
        int o = u * 4096 + rowa * 32 + ((g ^ ((rowa >> 1) & 3)) * 8);
        af[mi] = *reinterpret_cast<const bf16x8*>(&lAh[o]);
        if constexpr (SPLIT)
          af2[mi] = *reinterpret_cast<const bf16x8*>(&lAl[o]);
      }
#pragma unroll
      for (int ni = 0; ni < 4; ++ni) {
        int rowb = wn + ni * 16 + r;
        int o = u * 4096 + rowb * 32 + ((g ^ ((rowb >> 1) & 3)) * 8);
        bfh[ni] = *reinterpret_cast<const bf16x8*>(&lBh[o]);
        if constexpr (SPLIT)
          bf2v[ni] = *reinterpret_cast<const bf16x8*>(&lBl[o]);
      }
#pragma unroll
      for (int mi = 0; mi < 4; ++mi)
#pragma unroll
        for (int ni = 0; ni < 4; ++ni) {
          acc[mi][ni] = __builtin_amdgcn_mfma_f32_16x16x32_bf16(af[mi], bfh[ni], acc[mi][ni], 0, 0, 0);
          if constexpr (SPLIT) {
            acc[mi][ni] = __builtin_amdgcn_mfma_f32_16x16x32_bf16(af[mi], bf2v[ni], acc[mi][ni], 0, 0, 0);
            acc[mi][ni] = __builtin_amdgcn_mfma_f32_16x16x32_bf16(af2[mi], bfh[ni], acc[mi][ni], 0, 0, 0);
          }
        }
    }
  }

#pragma unroll
  for (int mi = 0; mi < 4; ++mi) {
#pragma unroll
    for (int ni = 0; ni < 4; ++ni) {
      long row0 = bm + wm + mi * 16 + g * 4;
      long col = bn + wn + ni * 16 + r;
#pragma unroll
      for (int q = 0; q < 4; ++q) {
        float v = acc[mi][ni][q];
        long row = row0 + q;
        if constexpr (MODE == 0) {
          unsigned short h = f2bf(v);
          ((unsigned short*)Cp)[row * (long)ldc + col] = h;
          C2[row * (long)ldc + col] = f2bf(v - bf2f(h));
        } else if constexpr (MODE == 2) {
          ((unsigned short*)Cp)[row * (long)ldc + col] = f2bf(v);
        } else {
          ((float*)Cp)[row * (long)ldc + col] = v;
        }
      }
    }
  }
}

// ---------------------------------------------------------------------------
// Round-10 scores kernel: BM=256 BN=128, 8 waves (4M x 2N), BK=32,
// 3-stage LDS (48KB/stage), counted vmcnt(6). SPLIT {hh,hl,lh}.
__launch_bounds__(512, 2)
__global__ void gemm8s(const unsigned short* __restrict__ Ah,
                       const unsigned short* __restrict__ Al, int lda,
                       const unsigned short* __restrict__ Bh,
                       const unsigned short* __restrict__ Bl, int ldb,
                       float* __restrict__ C, int ldc,
                       const float* __restrict__ mask,
                       const unsigned short* __restrict__ maskT,
                       float scale, int nkt) {
  // Per stage (ushort offsets): Ah 0..8191, Al 8192..16383,
  // Bh 16384..20479, Bl 20480..24575.  3 stages x 48KB = 144KB.
  __shared__ __align__(16) unsigned short lds[3][24576];

  const int t = threadIdx.x;          // 0..511
  const int w = t >> 6;               // wave 0..7
  const int lane = t & 63;
  const int g = lane >> 4;
  const int r = lane & 15;
  const int wr = w >> 1;              // 0..3  (M quarter)
  const int wc = w & 1;               // 0..1  (N half)
  const long bm = (long)blockIdx.x * 256;
  const long bn = (long)blockIdx.y * 128;

  // Staging map (XOR swizzle, round-7 involution): thread t covers rows
  // trow and trow+128 of A, row trow of B; granule ko = (t&3)^((t>>3)&3).
  const int trow = t >> 2;
  const int ko = (t & 3) ^ ((t >> 3) & 3);
  const unsigned short* gA0h = Ah + (bm + trow) * (long)lda + ko * 8;
  const unsigned short* gA1h = gA0h + 128 * (long)lda;
  const unsigned short* gA0l = Al + (bm + trow) * (long)lda + ko * 8;
  const unsigned short* gA1l = gA0l + 128 * (long)lda;
  const unsigned short* gB0h = Bh + (bn + trow) * (long)ldb + ko * 8;
  const unsigned short* gB0l = Bl + (bn + trow) * (long)ldb + ko * 8;
  const int dA0 = w * 512, dA1 = 4096 + w * 512;

  f32x4 acc[4][4];
  const f32x4 vzero = {0.f, 0.f, 0.f, 0.f};
#pragma unroll
  for (int mi = 0; mi < 4; ++mi)
#pragma unroll
    for (int ni = 0; ni < 4; ++ni) acc[mi][ni] = vzero;

  // Prologue: stage K-steps 0 and 1 (6 loads each, issue-order = count order).
#pragma unroll
  for (int s0 = 0; s0 < 2; ++s0) {
    long off = (long)s0 * 32;
    gl_lds16(gA0h + off, &lds[s0][dA0]);
    gl_lds16(gA1h + off, &lds[s0][dA1]);
    gl_lds16(gA0l + off, &lds[s0][8192 + dA0]);
    gl_lds16(gA1l + off, &lds[s0][8192 + dA1]);
    gl_lds16(gB0h + off, &lds[s0][16384 + dA0]);
    gl_lds16(gB0l + off, &lds[s0][20480 + dA0]);
  }

  for (int kt = 0; kt < nkt; ++kt) {
    const int st = kt % 3;
    const int nst = (kt + 2) % 3;
    const bool stg = (kt < nkt - 2);
    const long noff = (long)(kt + 2) * 32;
    // T4: wait own buffer; leave next step's 6 loads in flight.
    if (kt < nkt - 1) asm volatile("s_waitcnt vmcnt(6)" ::: "memory");
    else              asm volatile("s_waitcnt vmcnt(0)" ::: "memory");
    __syncthreads();

    bf16x8 bh[4], bl[4];
#pragma unroll
    for (int p = 0; p < 4; ++p) {
      if (p == 0) {
#pragma unroll
        for (int ni = 0; ni < 4; ++ni) {
          int rowb = wc * 64 + ni * 16 + r;
          int o = rowb * 32 + ((g ^ ((rowb >> 1) & 3)) * 8);
          bh[ni] = *reinterpret_cast<const bf16x8*>(&lds[st][16384 + o]);
          bl[ni] = *reinterpret_cast<const bf16x8*>(&lds[st][20480 + o]);
        }
      }
      bf16x8 ah, al;
      {
        int rowa = wr * 64 + p * 16 + r;
        int o = rowa * 32 + ((g ^ ((rowa >> 1) & 3)) * 8);
        ah = *reinterpret_cast<const bf16x8*>(&lds[st][o]);
        al = *reinterpret_cast<const bf16x8*>(&lds[st][8192 + o]);
      }
      if (stg && p == 0) {
        gl_lds16(gA0h + noff, &lds[nst][dA0]);
        gl_lds16(gA1h + noff, &lds[nst][dA1]);
      }
      if (stg && p == 1) {
        gl_lds16(gA0l + noff, &lds[nst][8192 + dA0]);
        gl_lds16(gA1l + noff, &lds[nst][8192 + dA1]);
      }
      if (stg && p == 2) {
        gl_lds16(gB0h + noff, &lds[nst][16384 + dA0]);
        gl_lds16(gB0l + noff, &lds[nst][20480 + dA0]);
      }
      __builtin_amdgcn_s_barrier();
      __builtin_amdgcn_s_setprio(1);
#pragma unroll
      for (int ni = 0; ni < 4; ++ni) {
        acc[p][ni] = __builtin_amdgcn_mfma_f32_16x16x32_bf16(ah, bh[ni], acc[p][ni], 0, 0, 0);
        acc[p][ni] = __builtin_amdgcn_mfma_f32_16x16x32_bf16(ah, bl[ni], acc[p][ni], 0, 0, 0);
        acc[p][ni] = __builtin_amdgcn_mfma_f32_16x16x32_bf16(al, bh[ni], acc[p][ni], 0, 0, 0);
      }
      __builtin_amdgcn_s_setprio(0);
      if (p < 3) __builtin_amdgcn_s_barrier();
    }
  }

  // Epilogue: scores = acc*scale + mask_filled^T.
  if (maskT) {
#pragma unroll
    for (int mi = 0; mi < 4; ++mi) {
#pragma unroll
      for (int ni = 0; ni < 4; ++ni) {
        long row0q = bm + wr * 64 + mi * 16 + g * 4;
        long col = bn + wc * 64 + ni * 16 + r;
#pragma unroll
        for (int q = 0; q < 4; ++q) {
          long row = row0q + q;
          float mv = bf2f(maskT[row * (long)S_LEN + col]);
          C[row * (long)ldc + col] = acc[mi][ni][q] * scale + mv;
        }
      }
    }
  } else {
#pragma unroll
    for (int mi = 0; mi < 4; ++mi) {
#pragma unroll
      for (int ni = 0; ni < 4; ++ni) {
        long row0q = bm + wr * 64 + mi * 16 + g * 4;
        long col = bn + wc * 64 + ni * 16 + r;
#pragma unroll
        for (int q = 0; q < 4; ++q) {
          long row = row0q + q;
          float mv = mask[col * (long)S_LEN + row];
          float v = acc[mi][ni][q] * scale;
          v = (mv == 0.0f) ? -__builtin_inff() : (v + mv);
          C[row * (long)ldc + col] = v;
        }
      }
    }
  }
}

// ---------------------------------------------------------------------------
// Row softmax, IN PLACE: fp32 row -> bf16 P in the same storage.
__launch_bounds__(256)
__global__ void softmax_rows(float* __restrict__ Sc) {
  const long row = blockIdx.x;
  float* sr = Sc + row * (long)S_LEN;
  unsigned short* pr = (unsigned short*)sr;
  const int t = threadIdx.x;
  const int lane = t & 63, wid = t >> 6;

  float4 x[4];
  float m = -3.0e38f;
#pragma unroll
  for (int i = 0; i < 4; ++i) {
    x[i] = reinterpret_cast<const float4*>(sr)[t + i * 256];
    m = fmaxf(m, fmaxf(fmaxf(x[i].x, x[i].y), fmaxf(x[i].z, x[i].w)));
  }
#pragma unroll
  for (int o = 32; o; o >>= 1) m = fmaxf(m, __shfl_xor(m, o));
  __shared__ float redm[4];
  __shared__ float reds[4];
  if (lane == 0) redm[wid] = m;
  __syncthreads();
  m = fmaxf(fmaxf(redm[0], redm[1]), fmaxf(redm[2], redm[3]));

  float e[16];
  float s = 0.f;
#pragma unroll
  for (int i = 0; i < 4; ++i) {
    e[i * 4 + 0] = __expf(x[i].x - m);
    e[i * 4 + 1] = __expf(x[i].y - m);
    e[i * 4 + 2] = __expf(x[i].z - m);
    e[i * 4 + 3] = __expf(x[i].w - m);
    s += e[i * 4 + 0] + e[i * 4 + 1] + e[i * 4 + 2] + e[i * 4 + 3];
  }
#pragma unroll
  for (int o = 32; o; o >>= 1) s += __shfl_xor(s, o);
  if (lane == 0) reds[wid] = s;
  __syncthreads();
  s = reds[0] + reds[1] + reds[2] + reds[3];
  float inv = 1.0f / s;
#pragma unroll
  for (int i = 0; i < 4; ++i) {
    ushort4 o4;
    o4.x = f2bf(e[i * 4 + 0] * inv);
    o4.y = f2bf(e[i * 4 + 1] * inv);
    o4.z = f2bf(e[i * 4 + 2] * inv);
    o4.w = f2bf(e[i * 4 + 3] * inv);
    reinterpret_cast<ushort4*>(pr)[t + i * 256] = o4;
  }
}

// ---------------------------------------------------------------------------
extern "C" void kernel_launch(void* const* d_in, const int* in_sizes, int n_in,
                              void* d_out, int out_size, void* d_ws, size_t ws_size,
                              hipStream_t stream) {
  const float* emb  = (const float*)d_in[0];
  const float* mask = (const float*)d_in[1];
  const float* wq   = (const float*)d_in[2];
  const float* wk   = (const float*)d_in[3];
  const float* wv   = (const float*)d_in[4];
  float* out = (float*)d_out;
  char* ws = (char*)d_ws;

  // Workspace layout (bytes): rounds 4-9 layout (106,954,752, proven) plus
  // optional maskT [4096][4096] bf16 (need2 = 140,509,184; proven round 9).
  const size_t need = 106954752;
  const size_t need2 = need + (size_t)S_LEN * S_LEN * 2;
  if (ws_size < need) return;
  const bool useT = (ws_size >= need2);

  unsigned short* Eh  = (unsigned short*)(ws);
  unsigned short* El  = (unsigned short*)(ws + 8388608);
  unsigned short* QMh = (unsigned short*)(ws + 16777216);
  unsigned short* QMl = (unsigned short*)(ws + 25165824);
  unsigned short* Vt  = QMh;  // alias, live only after scores
  unsigned short* MtH = (unsigned short*)(ws + 33554432);
  unsigned short* MtL = (unsigned short*)(ws + 35651584);
  unsigned short* Wvt = (unsigned short*)(ws + 37748736);
  float* scores       = (float*)(ws + 39845888);
  unsigned short* WqH = (unsigned short*)(ws + 39845888);
  unsigned short* WqL = (unsigned short*)(ws + 39845888 + 2097152);
  unsigned short* WkH = (unsigned short*)(ws + 39845888 + 4194304);
  unsigned short* WkL = (unsigned short*)(ws + 39845888 + 6291456);
  unsigned short* maskT = useT ? (unsigned short*)(ws + need) : nullptr;

  // ---- once: split weights, transpose Wv (+mask), precompute Mt -----------
  split32<<<1024, 256, 0, stream>>>(wq, WqH, WqL);
  split32<<<1024, 256, 0, stream>>>(wk, WkH, WkL);
  prep_wv<<<dim3(32, 32), dim3(32, 8), 0, stream>>>(wv, Wvt);
  if (useT)
    prep_maskT<<<dim3(128, 128), dim3(32, 8), 0, stream>>>(mask, maskT);
  gemm_bt<1, 0, 1><<<dim3(8, 8), 256, 0, stream>>>(
      WkH, WkL, 1024, WqH, WqL, 1024, (void*)MtH, 1024, MtL, 32);

  for (int b = 0; b < 2; ++b) {
    const float* embb = emb + (size_t)b * 4096 * 1024;
    float* outb = out + (size_t)b * 4096 * 1024;

    // 1) split embeddings into bf16 hi/lo
    split32<<<4096, 256, 0, stream>>>(embb, Eh, El);
    // 2) QM = E*Mt^T (SPLIT, 128^2 engine), hi/lo store
    gemm_bt<1, 0, 1><<<dim3(32, 8), 256, 0, stream>>>(
        Eh, El, 1024, MtH, MtL, 1024, (void*)QMh, 1024, QMl, 32);
    // 3) scores = (QM * E^T)/32 + mask_filled^T  (3-stage vmcnt(6) engine)
    gemm8s<<<dim3(16, 32), 512, 0, stream>>>(
        QMh, QMl, 1024, Eh, El, 1024, scores, 4096, mask, maskT, 0.03125f, 32);
    // 4) Vt = Wvt * E^T (plain bf16, BK=64; overwrites dead QMh region)
    gemm_bt<0, 2, 2><<<dim3(8, 32), 256, 0, stream>>>(
        Wvt, nullptr, 1024, Eh, nullptr, 1024, (void*)Vt, 4096, nullptr, 32);
    // 5) row softmax -> P bf16, in place (row stride 8192 ushorts)
    softmax_rows<<<4096, 256, 0, stream>>>(scores);
    // 6) out = P @ V (plain, BK=64), fp32 store
    gemm_bt<0, 3, 2><<<dim3(32, 8), 256, 0, stream>>>(
        (unsigned short*)scores, nullptr, 8192, Vt, nullptr, 4096,
        (void*)outb, 1024, nullptr, 128);
  }
}

// Round 11
// 578.780 us; speedup vs baseline: 1.0403x; 1.0386x over previous
//
#include <hip/hip_runtime.h>

// Self-attention B=2, S=4096, D=1024, fp32 in/out.
//
// Round-11: consolidation.
//   * scores: REVERT to round-9 BM=BN=256 2-stage kernel (96.5us proven;
//     round-10's BN=128 3-stage vmcnt(6) regressed to 109.5 -- wave tile
//     4x4 acc halved the MFMA:ds_read ratio and doubled block count).
//     One tweak: all 8 staging issues at phase 0 (was A@p0/B@p1) -> the
//     end-of-step drain gets one extra MFMA phase of latency cover.
//   * KEEP round-10's KU=2 (BK=64) on the 128^2 engine for PV/Vt (banked:
//     non-scores time 409 -> 382us).
// Algebra unchanged: QM trick + split-bf16 {hh,hl,lh}; XOR-swizzled LDS;
// bf16 maskT epilogue.

#define S_LEN 4096

typedef __bf16 bf16x8 __attribute__((ext_vector_type(8)));
typedef float f32x4 __attribute__((ext_vector_type(4)));

__device__ __forceinline__ unsigned short f2bf(float x) {
  unsigned u = __float_as_uint(x);
  unsigned r = u + 0x7fffu + ((u >> 16) & 1u);  // round-to-nearest-even
  return (unsigned short)(r >> 16);
}
__device__ __forceinline__ float bf2f(unsigned short h) {
  return __uint_as_float(((unsigned)h) << 16);
}

__device__ __forceinline__ void gl_lds16(const void* g, void* l) {
  __builtin_amdgcn_global_load_lds(
      (const __attribute__((address_space(1))) void*)g,
      (__attribute__((address_space(3))) void*)l, 16, 0, 0);
}

// ---------------------------------------------------------------------------
// split32: fp32 -> (hi, lo) bf16 pair, elementwise, float4-vectorized.
__launch_bounds__(256)
__global__ void split32(const float* __restrict__ e,
                        unsigned short* __restrict__ Eh,
                        unsigned short* __restrict__ El) {
  int i = blockIdx.x * 256 + threadIdx.x;  // float4 index
  float4 v = reinterpret_cast<const float4*>(e)[i];
  ushort4 h, l;
  h.x = f2bf(v.x); l.x = f2bf(v.x - bf2f(h.x));
  h.y = f2bf(v.y); l.y = f2bf(v.y - bf2f(h.y));
  h.z = f2bf(v.z); l.z = f2bf(v.z - bf2f(h.z));
  h.w = f2bf(v.w); l.w = f2bf(v.w - bf2f(h.w));
  reinterpret_cast<ushort4*>(Eh)[i] = h;
  reinterpret_cast<ushort4*>(El)[i] = l;
}

// ---------------------------------------------------------------------------
// prep_wv: Wv[d][e] -> Wvt[e][d] plain bf16. 32x32 LDS transpose.
__launch_bounds__(256)
__global__ void prep_wv(const float* __restrict__ wv, unsigned short* __restrict__ Wvt) {
  __shared__ float tile[32][33];
  const int bx = blockIdx.x * 32;
  const int by = blockIdx.y * 32;
  const int tx = threadIdx.x;
  const int ty = threadIdx.y;
#pragma unroll
  for (int j = 0; j < 4; ++j)
    tile[ty + j * 8][tx] = wv[(long)(by + ty + j * 8) * 1024 + bx + tx];
  __syncthreads();
#pragma unroll
  for (int j = 0; j < 4; ++j) {
    float v = tile[tx][ty + j * 8];
    Wvt[(long)(bx + ty + j * 8) * 1024 + by + tx] = f2bf(v);
  }
}

// ---------------------------------------------------------------------------
// prep_maskT: maskT[q][k] = bf16(mask_filled[k][q]), mask==0 -> -inf (0xFF80).
__launch_bounds__(256)
__global__ void prep_maskT(const float* __restrict__ mask,
                           unsigned short* __restrict__ maskT) {
  __shared__ float tile[32][33];
  const int bx = blockIdx.x * 32;  // q block
  const int by = blockIdx.y * 32;  // k block
  const int tx = threadIdx.x;
  const int ty = threadIdx.y;
#pragma unroll
  for (int j = 0; j < 4; ++j)
    tile[ty + j * 8][tx] = mask[(long)(by + ty + j * 8) * S_LEN + bx + tx];
  __syncthreads();
#pragma unroll
  for (int j = 0; j < 4; ++j) {
    float v = tile[tx][ty + j * 8];  // = mask[by+tx][bx+ty+j*8]
    unsigned short u = (v == 0.0f) ? (unsigned short)0xFF80 : f2bf(v);
    maskT[(long)(bx + ty + j * 8) * S_LEN + by + tx] = u;
  }
}

// ---------------------------------------------------------------------------
// 128^2 engine: NT GEMM with XOR-swizzled LDS. KU = K-unroll (subtiles of 32
// per barrier pair). MODE 0: hi/lo pair store  MODE 2: bf16  MODE 3: f32.
template <int SPLIT, int MODE, int KU>
__launch_bounds__(256)
__global__ void gemm_bt(const unsigned short* __restrict__ Ah,
                        const unsigned short* __restrict__ Al, int lda,
                        const unsigned short* __restrict__ Bh,
                        const unsigned short* __restrict__ Bl, int ldb,
                        void* __restrict__ Cp, int ldc,
                        unsigned short* __restrict__ C2, int kIters) {
  __shared__ unsigned short lAh[KU * 128 * 32];
  __shared__ unsigned short lBh[KU * 128 * 32];
  __shared__ unsigned short lAl[SPLIT ? 128 * 32 : 8];
  __shared__ unsigned short lBl[SPLIT ? 128 * 32 : 8];

  const int t = threadIdx.x;
  const int w = t >> 6;
  const int lane = t & 63;
  const int g = lane >> 4;
  const int r = lane & 15;
  const int wm = (w >> 1) * 64;
  const int wn = (w & 1) * 64;
  const long bm = (long)blockIdx.x * 128;
  const long bn = (long)blockIdx.y * 128;

  f32x4 acc[4][4];
  const f32x4 vzero = {0.f, 0.f, 0.f, 0.f};
#pragma unroll
  for (int mi = 0; mi < 4; ++mi)
#pragma unroll
    for (int ni = 0; ni < 4; ++ni) acc[mi][ni] = vzero;

  const int outer = kIters / KU;
  for (int kt = 0; kt < outer; ++kt) {
    __syncthreads();
    const long kbase = (long)kt * 32 * KU;
#pragma unroll
    for (int u = 0; u < KU; ++u) {
#pragma unroll
      for (int i = 0; i < 2; ++i) {
        int s = (i * 4 + w) * 64 + lane;
        int row = s >> 2;
        int ko = (s & 3) ^ ((row >> 1) & 3);
        long goffA = (bm + row) * (long)lda + kbase + u * 32 + ko * 8;
        long goffB = (bn + row) * (long)ldb + kbase + u * 32 + ko * 8;
        int lbase = u * 4096 + (i * 4 + w) * 512;
        gl_lds16(Ah + goffA, lAh + lbase);
        gl_lds16(Bh + goffB, lBh + lbase);
        if constexpr (SPLIT) {
          gl_lds16(Al + goffA, lAl + lbase);
          gl_lds16(Bl + goffB, lBl + lbase);
        }
      }
    }
    __syncthreads();

#pragma unroll
    for (int u = 0; u < KU; ++u) {
      bf16x8 af[4], bfh[4], af2[4], bf2v[4];
#pragma unroll
      for (int mi = 0; mi < 4; ++mi) {
        int rowa = wm + mi * 16 + r;
        int o = u * 4096 + rowa * 32 + ((g ^ ((rowa >> 1) & 3)) * 8);
        af[mi] = *reinterpret_cast<const bf16x8*>(&lAh[o]);
        if constexpr (SPLIT)
          af2[mi] = *reinterpret_cast<const bf16x8*>(&lAl[o]);
      }
#pragma unroll
      for (int ni = 0; ni < 4; ++ni) {
        int rowb = wn + ni * 16 + r;
        int o = u * 4096 + rowb * 32 + ((g ^ ((rowb >> 1) & 3)) * 8);
        bfh[ni] = *reinterpret_cast<const bf16x8*>(&lBh[o]);
        if constexpr (SPLIT)
          bf2v[ni] = *reinterpret_cast<const bf16x8*>(&lBl[o]);
      }
#pragma unroll
      for (int mi = 0; mi < 4; ++mi)
#pragma unroll
        for (int ni = 0; ni < 4; ++ni) {
          acc[mi][ni] = __builtin_amdgcn_mfma_f32_16x16x32_bf16(af[mi], bfh[ni], acc[mi][ni], 0, 0, 0);
          if constexpr (SPLIT) {
            acc[mi][ni] = __builtin_amdgcn_mfma_f32_16x16x32_bf16(af[mi], bf2v[ni], acc[mi][ni], 0, 0, 0);
            acc[mi][ni] = __builtin_amdgcn_mfma_f32_16x16x32_bf16(af2[mi], bfh[ni], acc[mi][ni], 0, 0, 0);
          }
        }
    }
  }

#pragma unroll
  for (int mi = 0; mi < 4; ++mi) {
#pragma unroll
    for (int ni = 0; ni < 4; ++ni) {
      long row0 = bm + wm + mi * 16 + g * 4;
      long col = bn + wn + ni * 16 + r;
#pragma unroll
      for (int q = 0; q < 4; ++q) {
        float v = acc[mi][ni][q];
        long row = row0 + q;
        if constexpr (MODE == 0) {
          unsigned short h = f2bf(v);
          ((unsigned short*)Cp)[row * (long)ldc + col] = h;
          C2[row * (long)ldc + col] = f2bf(v - bf2f(h));
        } else if constexpr (MODE == 2) {
          ((unsigned short*)Cp)[row * (long)ldc + col] = f2bf(v);
        } else {
          ((float*)Cp)[row * (long)ldc + col] = v;
        }
      }
    }
  }
}

// ---------------------------------------------------------------------------
// Scores kernel (round-9 geometry): 256^2, 8 waves (2M x 4N), BK=32,
// 2-stage LDS dbuf, 4 phases/K-step, all staging issued at phase 0.
// C[m][n] = (sum_k A[m][k]*B[n][k]) * scale + mask_filled^T, fp32 store.
__launch_bounds__(512, 2)
__global__ void gemm8s(const unsigned short* __restrict__ Ah,
                       const unsigned short* __restrict__ Al, int lda,
                       const unsigned short* __restrict__ Bh,
                       const unsigned short* __restrict__ Bl, int ldb,
                       float* __restrict__ C, int ldc,
                       const float* __restrict__ mask,
                       const unsigned short* __restrict__ maskT,
                       float scale, int nkt) {
  __shared__ __align__(16) unsigned short lds[4][2][8192];

  const int t = threadIdx.x;          // 0..511
  const int w = t >> 6;               // wave 0..7
  const int lane = t & 63;
  const int g = lane >> 4;
  const int r = lane & 15;
  const int wr = w >> 2;              // 0..1  (M)
  const int wc = w & 3;               // 0..3  (N)
  const long bm = (long)blockIdx.x * 256;
  const long bn = (long)blockIdx.y * 256;

  const int row0 = t >> 2;
  const int ko = (t & 3) ^ ((t >> 3) & 3);
  const unsigned short* pAh = Ah + (bm + row0) * (long)lda + ko * 8;
  const unsigned short* pAl = Al + (bm + row0) * (long)lda + ko * 8;
  const unsigned short* pBh = Bh + (bn + row0) * (long)ldb + ko * 8;
  const unsigned short* pBl = Bl + (bn + row0) * (long)ldb + ko * 8;

  f32x4 acc[8][4];
  const f32x4 vzero = {0.f, 0.f, 0.f, 0.f};
#pragma unroll
  for (int mi = 0; mi < 8; ++mi)
#pragma unroll
    for (int ni = 0; ni < 4; ++ni) acc[mi][ni] = vzero;

  // Prologue: stage K-step 0 into buf 0.
#pragma unroll
  for (int T = 0; T < 4; ++T) {
    const unsigned short* sp = (T == 0) ? pAh : (T == 1) ? pAl : (T == 2) ? pBh : pBl;
    long ld = (T < 2) ? lda : ldb;
    gl_lds16(sp, &lds[T][0][w * 512]);
    gl_lds16(sp + 128 * ld, &lds[T][0][4096 + w * 512]);
  }
  asm volatile("s_waitcnt vmcnt(0)" ::: "memory");
  __syncthreads();

  for (int kt = 0; kt < nkt; ++kt) {
    const int cb = kt & 1, nb = cb ^ 1;
    const bool stg = (kt < nkt - 1);
    bf16x8 bh[4], bl[4];
#pragma unroll
    for (int p = 0; p < 4; ++p) {
      if (p == 0) {
#pragma unroll
        for (int ni = 0; ni < 4; ++ni) {
          int rowb = wc * 64 + ni * 16 + r;
          int o = rowb * 32 + ((g ^ ((rowb >> 1) & 3)) * 8);
          bh[ni] = *reinterpret_cast<const bf16x8*>(&lds[2][cb][o]);
          bl[ni] = *reinterpret_cast<const bf16x8*>(&lds[3][cb][o]);
        }
      }
      bf16x8 ah[2], al[2];
#pragma unroll
      for (int i = 0; i < 2; ++i) {
        int rowa = wr * 128 + (2 * p + i) * 16 + r;
        int o = rowa * 32 + ((g ^ ((rowa >> 1) & 3)) * 8);
        ah[i] = *reinterpret_cast<const bf16x8*>(&lds[0][cb][o]);
        al[i] = *reinterpret_cast<const bf16x8*>(&lds[1][cb][o]);
      }
      // All 8 staging issues at phase 0 (one extra phase of drain cover).
      if (stg && p == 0) {
        gl_lds16(pAh + 32, &lds[0][nb][w * 512]);
        gl_lds16(pAh + 32 + 128 * (long)lda, &lds[0][nb][4096 + w * 512]);
        gl_lds16(pAl + 32, &lds[1][nb][w * 512]);
        gl_lds16(pAl + 32 + 128 * (long)lda, &lds[1][nb][4096 + w * 512]);
        gl_lds16(pBh + 32, &lds[2][nb][w * 512]);
        gl_lds16(pBh + 32 + 128 * (long)ldb, &lds[2][nb][4096 + w * 512]);
        gl_lds16(pBl + 32, &lds[3][nb][w * 512]);
        gl_lds16(pBl + 32 + 128 * (long)ldb, &lds[3][nb][4096 + w * 512]);
      }
      __builtin_amdgcn_s_barrier();
      __builtin_amdgcn_s_setprio(1);
#pragma unroll
      for (int i = 0; i < 2; ++i) {
        const int mi = 2 * p + i;
#pragma unroll
        for (int ni = 0; ni < 4; ++ni) {
          acc[mi][ni] = __builtin_amdgcn_mfma_f32_16x16x32_bf16(ah[i], bh[ni], acc[mi][ni], 0, 0, 0);
          acc[mi][ni] = __builtin_amdgcn_mfma_f32_16x16x32_bf16(ah[i], bl[ni], acc[mi][ni], 0, 0, 0);
          acc[mi][ni] = __builtin_amdgcn_mfma_f32_16x16x32_bf16(al[i], bh[ni], acc[mi][ni], 0, 0, 0);
        }
      }
      __builtin_amdgcn_s_setprio(0);
      if (p < 3) __builtin_amdgcn_s_barrier();
    }
    asm volatile("s_waitcnt vmcnt(0)" ::: "memory");
    __syncthreads();
    pAh += 32; pAl += 32; pBh += 32; pBl += 32;
  }

  // Epilogue: scores = acc*scale + mask_filled^T.
  if (maskT) {
#pragma unroll
    for (int mi = 0; mi < 8; ++mi) {
#pragma unroll
      for (int ni = 0; ni < 4; ++ni) {
        long row0q = bm + wr * 128 + mi * 16 + g * 4;
        long col = bn + wc * 64 + ni * 16 + r;
#pragma unroll
        for (int q = 0; q < 4; ++q) {
          long row = row0q + q;
          float mv = bf2f(maskT[row * (long)S_LEN + col]);
          C[row * (long)ldc + col] = acc[mi][ni][q] * scale + mv;
        }
      }
    }
  } else {
#pragma unroll
    for (int mi = 0; mi < 8; ++mi) {
#pragma unroll
      for (int ni = 0; ni < 4; ++ni) {
        long row0q = bm + wr * 128 + mi * 16 + g * 4;
        long col = bn + wc * 64 + ni * 16 + r;
#pragma unroll
        for (int q = 0; q < 4; ++q) {
          long row = row0q + q;
          float mv = mask[col * (long)S_LEN + row];
          float v = acc[mi][ni][q] * scale;
          v = (mv == 0.0f) ? -__builtin_inff() : (v + mv);
          C[row * (long)ldc + col] = v;
        }
      }
    }
  }
}

// ---------------------------------------------------------------------------
// Row softmax, IN PLACE: fp32 row -> bf16 P in the same storage.
__launch_bounds__(256)
__global__ void softmax_rows(float* __restrict__ Sc) {
  const long row = blockIdx.x;
  float* sr = Sc + row * (long)S_LEN;
  unsigned short* pr = (unsigned short*)sr;
  const int t = threadIdx.x;
  const int lane = t & 63, wid = t >> 6;

  float4 x[4];
  float m = -3.0e38f;
#pragma unroll
  for (int i = 0; i < 4; ++i) {
    x[i] = reinterpret_cast<const float4*>(sr)[t + i * 256];
    m = fmaxf(m, fmaxf(fmaxf(x[i].x, x[i].y), fmaxf(x[i].z, x[i].w)));
  }
#pragma unroll
  for (int o = 32; o; o >>= 1) m = fmaxf(m, __shfl_xor(m, o));
  __shared__ float redm[4];
  __shared__ float reds[4];
  if (lane == 0) redm[wid] = m;
  __syncthreads();
  m = fmaxf(fmaxf(redm[0], redm[1]), fmaxf(redm[2], redm[3]));

  float e[16];
  float s = 0.f;
#pragma unroll
  for (int i = 0; i < 4; ++i) {
    e[i * 4 + 0] = __expf(x[i].x - m);
    e[i * 4 + 1] = __expf(x[i].y - m);
    e[i * 4 + 2] = __expf(x[i].z - m);
    e[i * 4 + 3] = __expf(x[i].w - m);
    s += e[i * 4 + 0] + e[i * 4 + 1] + e[i * 4 + 2] + e[i * 4 + 3];
  }
#pragma unroll
  for (int o = 32; o; o >>= 1) s += __shfl_xor(s, o);
  if (lane == 0) reds[wid] = s;
  __syncthreads();
  s = reds[0] + reds[1] + reds[2] + reds[3];
  float inv = 1.0f / s;
#pragma unroll
  for (int i = 0; i < 4; ++i) {
    ushort4 o4;
    o4.x = f2bf(e[i * 4 + 0] * inv);
    o4.y = f2bf(e[i * 4 + 1] * inv);
    o4.z = f2bf(e[i * 4 + 2] * inv);
    o4.w = f2bf(e[i * 4 + 3] * inv);
    reinterpret_cast<ushort4*>(pr)[t + i * 256] = o4;
  }
}

// ---------------------------------------------------------------------------
extern "C" void kernel_launch(void* const* d_in, const int* in_sizes, int n_in,
                              void* d_out, int out_size, void* d_ws, size_t ws_size,
                              hipStream_t stream) {
  const float* emb  = (const float*)d_in[0];
  const float* mask = (const float*)d_in[1];
  const float* wq   = (const float*)d_in[2];
  const float* wk   = (const float*)d_in[3];
  const float* wv   = (const float*)d_in[4];
  float* out = (float*)d_out;
  char* ws = (char*)d_ws;

  // Workspace layout (bytes): rounds 4-10 layout (106,954,752, proven) plus
  // optional maskT [4096][4096] bf16 (need2 = 140,509,184; proven rounds 9/10).
  const size_t need = 106954752;
  const size_t need2 = need + (size_t)S_LEN * S_LEN * 2;
  if (ws_size < need) return;
  const bool useT = (ws_size >= need2);

  unsigned short* Eh  = (unsigned short*)(ws);
  unsigned short* El  = (unsigned short*)(ws + 8388608);
  unsigned short* QMh = (unsigned short*)(ws + 16777216);
  unsigned short* QMl = (unsigned short*)(ws + 25165824);
  unsigned short* Vt  = QMh;  // alias, live only after scores
  unsigned short* MtH = (unsigned short*)(ws + 33554432);
  unsigned short* MtL = (unsigned short*)(ws + 35651584);
  unsigned short* Wvt = (unsigned short*)(ws + 37748736);
  float* scores       = (float*)(ws + 39845888);
  unsigned short* WqH = (unsigned short*)(ws + 39845888);
  unsigned short* WqL = (unsigned short*)(ws + 39845888 + 2097152);
  unsigned short* WkH = (unsigned short*)(ws + 39845888 + 4194304);
  unsigned short* WkL = (unsigned short*)(ws + 39845888 + 6291456);
  unsigned short* maskT = useT ? (unsigned short*)(ws + need) : nullptr;

  // ---- once: split weights, transpose Wv (+mask), precompute Mt -----------
  split32<<<1024, 256, 0, stream>>>(wq, WqH, WqL);
  split32<<<1024, 256, 0, stream>>>(wk, WkH, WkL);
  prep_wv<<<dim3(32, 32), dim3(32, 8), 0, stream>>>(wv, Wvt);
  if (useT)
    prep_maskT<<<dim3(128, 128), dim3(32, 8), 0, stream>>>(mask, maskT);
  gemm_bt<1, 0, 1><<<dim3(8, 8), 256, 0, stream>>>(
      WkH, WkL, 1024, WqH, WqL, 1024, (void*)MtH, 1024, MtL, 32);

  for (int b = 0; b < 2; ++b) {
    const float* embb = emb + (size_t)b * 4096 * 1024;
    float* outb = out + (size_t)b * 4096 * 1024;

    // 1) split embeddings into bf16 hi/lo
    split32<<<4096, 256, 0, stream>>>(embb, Eh, El);
    // 2) QM = E*Mt^T (SPLIT, 128^2 engine), hi/lo store
    gemm_bt<1, 0, 1><<<dim3(32, 8), 256, 0, stream>>>(
        Eh, El, 1024, MtH, MtL, 1024, (void*)QMh, 1024, QMl, 32);
    // 3) scores = (QM * E^T)/32 + mask_filled^T  (256^2 8-wave engine)
    gemm8s<<<dim3(16, 16), 512, 0, stream>>>(
        QMh, QMl, 1024, Eh, El, 1024, scores, 4096, mask, maskT, 0.03125f, 32);
    // 4) Vt = Wvt * E^T (plain bf16, BK=64; overwrites dead QMh region)
    gemm_bt<0, 2, 2><<<dim3(8, 32), 256, 0, stream>>>(
        Wvt, nullptr, 1024, Eh, nullptr, 1024, (void*)Vt, 4096, nullptr, 32);
    // 5) row softmax -> P bf16, in place (row stride 8192 ushorts)
    softmax_rows<<<4096, 256, 0, stream>>>(scores);
    // 6) out = P @ V (plain, BK=64), fp32 store
    gemm_bt<0, 3, 2><<<dim3(32, 8), 256, 0, stream>>>(
        (unsigned short*)scores, nullptr, 8192, Vt, nullptr, 4096,
        (void*)outb, 1024, nullptr, 128);
  }
}

// Round 12
// 572.377 us; speedup vs baseline: 1.0519x; 1.0112x over previous
//
#include <hip/hip_runtime.h>

// Self-attention B=2, S=4096, D=1024, fp32 in/out.
//
// Round-12: recombine proven bests.
//   * gemm8s staging REVERTED to round-9 placement (A tiles @ phase 0,
//     B tiles @ phase 1). Round-11's all-at-p0 burst regressed scores
//     96.5 -> 103.5us (issue contention in p0 + 8 extra VGPR); the split
//     placement already gives B-loads ~3 MFMA phases of drain cover.
//   * KEEP round-11's KU=2 (BK=64) 128^2 engine for PV/Vt (non-scores
//     372us, proven).
// Algebra unchanged: QM trick + split-bf16 {hh,hl,lh}; XOR-swizzled LDS
// (conflicts=0); bf16 maskT epilogue (-inf pre-encoded).

#define S_LEN 4096

typedef __bf16 bf16x8 __attribute__((ext_vector_type(8)));
typedef float f32x4 __attribute__((ext_vector_type(4)));

__device__ __forceinline__ unsigned short f2bf(float x) {
  unsigned u = __float_as_uint(x);
  unsigned r = u + 0x7fffu + ((u >> 16) & 1u);  // round-to-nearest-even
  return (unsigned short)(r >> 16);
}
__device__ __forceinline__ float bf2f(unsigned short h) {
  return __uint_as_float(((unsigned)h) << 16);
}

__device__ __forceinline__ void gl_lds16(const void* g, void* l) {
  __builtin_amdgcn_global_load_lds(
      (const __attribute__((address_space(1))) void*)g,
      (__attribute__((address_space(3))) void*)l, 16, 0, 0);
}

// ---------------------------------------------------------------------------
// split32: fp32 -> (hi, lo) bf16 pair, elementwise, float4-vectorized.
__launch_bounds__(256)
__global__ void split32(const float* __restrict__ e,
                        unsigned short* __restrict__ Eh,
                        unsigned short* __restrict__ El) {
  int i = blockIdx.x * 256 + threadIdx.x;  // float4 index
  float4 v = reinterpret_cast<const float4*>(e)[i];
  ushort4 h, l;
  h.x = f2bf(v.x); l.x = f2bf(v.x - bf2f(h.x));
  h.y = f2bf(v.y); l.y = f2bf(v.y - bf2f(h.y));
  h.z = f2bf(v.z); l.z = f2bf(v.z - bf2f(h.z));
  h.w = f2bf(v.w); l.w = f2bf(v.w - bf2f(h.w));
  reinterpret_cast<ushort4*>(Eh)[i] = h;
  reinterpret_cast<ushort4*>(El)[i] = l;
}

// ---------------------------------------------------------------------------
// prep_wv: Wv[d][e] -> Wvt[e][d] plain bf16. 32x32 LDS transpose.
__launch_bounds__(256)
__global__ void prep_wv(const float* __restrict__ wv, unsigned short* __restrict__ Wvt) {
  __shared__ float tile[32][33];
  const int bx = blockIdx.x * 32;
  const int by = blockIdx.y * 32;
  const int tx = threadIdx.x;
  const int ty = threadIdx.y;
#pragma unroll
  for (int j = 0; j < 4; ++j)
    tile[ty + j * 8][tx] = wv[(long)(by + ty + j * 8) * 1024 + bx + tx];
  __syncthreads();
#pragma unroll
  for (int j = 0; j < 4; ++j) {
    float v = tile[tx][ty + j * 8];
    Wvt[(long)(bx + ty + j * 8) * 1024 + by + tx] = f2bf(v);
  }
}

// ---------------------------------------------------------------------------
// prep_maskT: maskT[q][k] = bf16(mask_filled[k][q]), mask==0 -> -inf (0xFF80).
__launch_bounds__(256)
__global__ void prep_maskT(const float* __restrict__ mask,
                           unsigned short* __restrict__ maskT) {
  __shared__ float tile[32][33];
  const int bx = blockIdx.x * 32;  // q block
  const int by = blockIdx.y * 32;  // k block
  const int tx = threadIdx.x;
  const int ty = threadIdx.y;
#pragma unroll
  for (int j = 0; j < 4; ++j)
    tile[ty + j * 8][tx] = mask[(long)(by + ty + j * 8) * S_LEN + bx + tx];
  __syncthreads();
#pragma unroll
  for (int j = 0; j < 4; ++j) {
    float v = tile[tx][ty + j * 8];  // = mask[by+tx][bx+ty+j*8]
    unsigned short u = (v == 0.0f) ? (unsigned short)0xFF80 : f2bf(v);
    maskT[(long)(bx + ty + j * 8) * S_LEN + by + tx] = u;
  }
}

// ---------------------------------------------------------------------------
// 128^2 engine: NT GEMM with XOR-swizzled LDS. KU = K-unroll (subtiles of 32
// per barrier pair). MODE 0: hi/lo pair store  MODE 2: bf16  MODE 3: f32.
template <int SPLIT, int MODE, int KU>
__launch_bounds__(256)
__global__ void gemm_bt(const unsigned short* __restrict__ Ah,
                        const unsigned short* __restrict__ Al, int lda,
                        const unsigned short* __restrict__ Bh,
                        const unsigned short* __restrict__ Bl, int ldb,
                        void* __restrict__ Cp, int ldc,
                        unsigned short* __restrict__ C2, int kIters) {
  __shared__ unsigned short lAh[KU * 128 * 32];
  __shared__ unsigned short lBh[KU * 128 * 32];
  __shared__ unsigned short lAl[SPLIT ? 128 * 32 : 8];
  __shared__ unsigned short lBl[SPLIT ? 128 * 32 : 8];

  const int t = threadIdx.x;
  const int w = t >> 6;
  const int lane = t & 63;
  const int g = lane >> 4;
  const int r = lane & 15;
  const int wm = (w >> 1) * 64;
  const int wn = (w & 1) * 64;
  const long bm = (long)blockIdx.x * 128;
  const long bn = (long)blockIdx.y * 128;

  f32x4 acc[4][4];
  const f32x4 vzero = {0.f, 0.f, 0.f, 0.f};
#pragma unroll
  for (int mi = 0; mi < 4; ++mi)
#pragma unroll
    for (int ni = 0; ni < 4; ++ni) acc[mi][ni] = vzero;

  const int outer = kIters / KU;
  for (int kt = 0; kt < outer; ++kt) {
    __syncthreads();
    const long kbase = (long)kt * 32 * KU;
#pragma unroll
    for (int u = 0; u < KU; ++u) {
#pragma unroll
      for (int i = 0; i < 2; ++i) {
        int s = (i * 4 + w) * 64 + lane;
        int row = s >> 2;
        int ko = (s & 3) ^ ((row >> 1) & 3);
        long goffA = (bm + row) * (long)lda + kbase + u * 32 + ko * 8;
        long goffB = (bn + row) * (long)ldb + kbase + u * 32 + ko * 8;
        int lbase = u * 4096 + (i * 4 + w) * 512;
        gl_lds16(Ah + goffA, lAh + lbase);
        gl_lds16(Bh + goffB, lBh + lbase);
        if constexpr (SPLIT) {
          gl_lds16(Al + goffA, lAl + lbase);
          gl_lds16(Bl + goffB, lBl + lbase);
        }
      }
    }
    __syncthreads();

#pragma unroll
    for (int u = 0; u < KU; ++u) {
      bf16x8 af[4], bfh[4], af2[4], bf2v[4];
#pragma unroll
      for (int mi = 0; mi < 4; ++mi) {
        int rowa = wm + mi * 16 + r;
        int o = u * 4096 + rowa * 32 + ((g ^ ((rowa >> 1) & 3)) * 8);
        af[mi] = *reinterpret_cast<const bf16x8*>(&lAh[o]);
        if constexpr (SPLIT)
          af2[mi] = *reinterpret_cast<const bf16x8*>(&lAl[o]);
      }
#pragma unroll
      for (int ni = 0; ni < 4; ++ni) {
        int rowb = wn + ni * 16 + r;
        int o = u * 4096 + rowb * 32 + ((g ^ ((rowb >> 1) & 3)) * 8);
        bfh[ni] = *reinterpret_cast<const bf16x8*>(&lBh[o]);
        if constexpr (SPLIT)
          bf2v[ni] = *reinterpret_cast<const bf16x8*>(&lBl[o]);
      }
#pragma unroll
      for (int mi = 0; mi < 4; ++mi)
#pragma unroll
        for (int ni = 0; ni < 4; ++ni) {
          acc[mi][ni] = __builtin_amdgcn_mfma_f32_16x16x32_bf16(af[mi], bfh[ni], acc[mi][ni], 0, 0, 0);
          if constexpr (SPLIT) {
            acc[mi][ni] = __builtin_amdgcn_mfma_f32_16x16x32_bf16(af[mi], bf2v[ni], acc[mi][ni], 0, 0, 0);
            acc[mi][ni] = __builtin_amdgcn_mfma_f32_16x16x32_bf16(af2[mi], bfh[ni], acc[mi][ni], 0, 0, 0);
          }
        }
    }
  }

#pragma unroll
  for (int mi = 0; mi < 4; ++mi) {
#pragma unroll
    for (int ni = 0; ni < 4; ++ni) {
      long row0 = bm + wm + mi * 16 + g * 4;
      long col = bn + wn + ni * 16 + r;
#pragma unroll
      for (int q = 0; q < 4; ++q) {
        float v = acc[mi][ni][q];
        long row = row0 + q;
        if constexpr (MODE == 0) {
          unsigned short h = f2bf(v);
          ((unsigned short*)Cp)[row * (long)ldc + col] = h;
          C2[row * (long)ldc + col] = f2bf(v - bf2f(h));
        } else if constexpr (MODE == 2) {
          ((unsigned short*)Cp)[row * (long)ldc + col] = f2bf(v);
        } else {
          ((float*)Cp)[row * (long)ldc + col] = v;
        }
      }
    }
  }
}

// ---------------------------------------------------------------------------
// Scores kernel (round-9 geometry + staging placement): 256^2, 8 waves
// (2M x 4N), BK=32, 2-stage LDS dbuf, 4 phases/K-step, staging A@p0 B@p1.
// C[m][n] = (sum_k A[m][k]*B[n][k]) * scale + mask_filled^T, fp32 store.
__launch_bounds__(512, 2)
__global__ void gemm8s(const unsigned short* __restrict__ Ah,
                       const unsigned short* __restrict__ Al, int lda,
                       const unsigned short* __restrict__ Bh,
                       const unsigned short* __restrict__ Bl, int ldb,
                       float* __restrict__ C, int ldc,
                       const float* __restrict__ mask,
                       const unsigned short* __restrict__ maskT,
                       float scale, int nkt) {
  __shared__ __align__(16) unsigned short lds[4][2][8192];

  const int t = threadIdx.x;          // 0..511
  const int w = t >> 6;               // wave 0..7
  const int lane = t & 63;
  const int g = lane >> 4;
  const int r = lane & 15;
  const int wr = w >> 2;              // 0..1  (M)
  const int wc = w & 3;               // 0..3  (N)
  const long bm = (long)blockIdx.x * 256;
  const long bn = (long)blockIdx.y * 256;

  const int row0 = t >> 2;
  const int ko = (t & 3) ^ ((t >> 3) & 3);
  const unsigned short* pAh = Ah + (bm + row0) * (long)lda + ko * 8;
  const unsigned short* pAl = Al + (bm + row0) * (long)lda + ko * 8;
  const unsigned short* pBh = Bh + (bn + row0) * (long)ldb + ko * 8;
  const unsigned short* pBl = Bl + (bn + row0) * (long)ldb + ko * 8;

  f32x4 acc[8][4];
  const f32x4 vzero = {0.f, 0.f, 0.f, 0.f};
#pragma unroll
  for (int mi = 0; mi < 8; ++mi)
#pragma unroll
    for (int ni = 0; ni < 4; ++ni) acc[mi][ni] = vzero;

  // Prologue: stage K-step 0 into buf 0.
#pragma unroll
  for (int T = 0; T < 4; ++T) {
    const unsigned short* sp = (T == 0) ? pAh : (T == 1) ? pAl : (T == 2) ? pBh : pBl;
    long ld = (T < 2) ? lda : ldb;
    gl_lds16(sp, &lds[T][0][w * 512]);
    gl_lds16(sp + 128 * ld, &lds[T][0][4096 + w * 512]);
  }
  asm volatile("s_waitcnt vmcnt(0)" ::: "memory");
  __syncthreads();

  for (int kt = 0; kt < nkt; ++kt) {
    const int cb = kt & 1, nb = cb ^ 1;
    const bool stg = (kt < nkt - 1);
    bf16x8 bh[4], bl[4];
#pragma unroll
    for (int p = 0; p < 4; ++p) {
      if (p == 0) {
#pragma unroll
        for (int ni = 0; ni < 4; ++ni) {
          int rowb = wc * 64 + ni * 16 + r;
          int o = rowb * 32 + ((g ^ ((rowb >> 1) & 3)) * 8);
          bh[ni] = *reinterpret_cast<const bf16x8*>(&lds[2][cb][o]);
          bl[ni] = *reinterpret_cast<const bf16x8*>(&lds[3][cb][o]);
        }
      }
      bf16x8 ah[2], al[2];
#pragma unroll
      for (int i = 0; i < 2; ++i) {
        int rowa = wr * 128 + (2 * p + i) * 16 + r;
        int o = rowa * 32 + ((g ^ ((rowa >> 1) & 3)) * 8);
        ah[i] = *reinterpret_cast<const bf16x8*>(&lds[0][cb][o]);
        al[i] = *reinterpret_cast<const bf16x8*>(&lds[1][cb][o]);
      }
      // Staging: A tiles at phase 0, B tiles at phase 1 (round-9-proven).
      if (stg && p == 0) {
        gl_lds16(pAh + 32, &lds[0][nb][w * 512]);
        gl_lds16(pAh + 32 + 128 * (long)lda, &lds[0][nb][4096 + w * 512]);
        gl_lds16(pAl + 32, &lds[1][nb][w * 512]);
        gl_lds16(pAl + 32 + 128 * (long)lda, &lds[1][nb][4096 + w * 512]);
      }
      if (stg && p == 1) {
        gl_lds16(pBh + 32, &lds[2][nb][w * 512]);
        gl_lds16(pBh + 32 + 128 * (long)ldb, &lds[2][nb][4096 + w * 512]);
        gl_lds16(pBl + 32, &lds[3][nb][w * 512]);
        gl_lds16(pBl + 32 + 128 * (long)ldb, &lds[3][nb][4096 + w * 512]);
      }
      __builtin_amdgcn_s_barrier();
      __builtin_amdgcn_s_setprio(1);
#pragma unroll
      for (int i = 0; i < 2; ++i) {
        const int mi = 2 * p + i;
#pragma unroll
        for (int ni = 0; ni < 4; ++ni) {
          acc[mi][ni] = __builtin_amdgcn_mfma_f32_16x16x32_bf16(ah[i], bh[ni], acc[mi][ni], 0, 0, 0);
          acc[mi][ni] = __builtin_amdgcn_mfma_f32_16x16x32_bf16(ah[i], bl[ni], acc[mi][ni], 0, 0, 0);
          acc[mi][ni] = __builtin_amdgcn_mfma_f32_16x16x32_bf16(al[i], bh[ni], acc[mi][ni], 0, 0, 0);
        }
      }
      __builtin_amdgcn_s_setprio(0);
      if (p < 3) __builtin_amdgcn_s_barrier();
    }
    asm volatile("s_waitcnt vmcnt(0)" ::: "memory");
    __syncthreads();
    pAh += 32; pAl += 32; pBh += 32; pBl += 32;
  }

  // Epilogue: scores = acc*scale + mask_filled^T.
  if (maskT) {
#pragma unroll
    for (int mi = 0; mi < 8; ++mi) {
#pragma unroll
      for (int ni = 0; ni < 4; ++ni) {
        long row0q = bm + wr * 128 + mi * 16 + g * 4;
        long col = bn + wc * 64 + ni * 16 + r;
#pragma unroll
        for (int q = 0; q < 4; ++q) {
          long row = row0q + q;
          float mv = bf2f(maskT[row * (long)S_LEN + col]);
          C[row * (long)ldc + col] = acc[mi][ni][q] * scale + mv;
        }
      }
    }
  } else {
#pragma unroll
    for (int mi = 0; mi < 8; ++mi) {
#pragma unroll
      for (int ni = 0; ni < 4; ++ni) {
        long row0q = bm + wr * 128 + mi * 16 + g * 4;
        long col = bn + wc * 64 + ni * 16 + r;
#pragma unroll
        for (int q = 0; q < 4; ++q) {
          long row = row0q + q;
          float mv = mask[col * (long)S_LEN + row];
          float v = acc[mi][ni][q] * scale;
          v = (mv == 0.0f) ? -__builtin_inff() : (v + mv);
          C[row * (long)ldc + col] = v;
        }
      }
    }
  }
}

// ---------------------------------------------------------------------------
// Row softmax, IN PLACE: fp32 row -> bf16 P in the same storage.
__launch_bounds__(256)
__global__ void softmax_rows(float* __restrict__ Sc) {
  const long row = blockIdx.x;
  float* sr = Sc + row * (long)S_LEN;
  unsigned short* pr = (unsigned short*)sr;
  const int t = threadIdx.x;
  const int lane = t & 63, wid = t >> 6;

  float4 x[4];
  float m = -3.0e38f;
#pragma unroll
  for (int i = 0; i < 4; ++i) {
    x[i] = reinterpret_cast<const float4*>(sr)[t + i * 256];
    m = fmaxf(m, fmaxf(fmaxf(x[i].x, x[i].y), fmaxf(x[i].z, x[i].w)));
  }
#pragma unroll
  for (int o = 32; o; o >>= 1) m = fmaxf(m, __shfl_xor(m, o));
  __shared__ float redm[4];
  __shared__ float reds[4];
  if (lane == 0) redm[wid] = m;
  __syncthreads();
  m = fmaxf(fmaxf(redm[0], redm[1]), fmaxf(redm[2], redm[3]));

  float e[16];
  float s = 0.f;
#pragma unroll
  for (int i = 0; i < 4; ++i) {
    e[i * 4 + 0] = __expf(x[i].x - m);
    e[i * 4 + 1] = __expf(x[i].y - m);
    e[i * 4 + 2] = __expf(x[i].z - m);
    e[i * 4 + 3] = __expf(x[i].w - m);
    s += e[i * 4 + 0] + e[i * 4 + 1] + e[i * 4 + 2] + e[i * 4 + 3];
  }
#pragma unroll
  for (int o = 32; o; o >>= 1) s += __shfl_xor(s, o);
  if (lane == 0) reds[wid] = s;
  __syncthreads();
  s = reds[0] + reds[1] + reds[2] + reds[3];
  float inv = 1.0f / s;
#pragma unroll
  for (int i = 0; i < 4; ++i) {
    ushort4 o4;
    o4.x = f2bf(e[i * 4 + 0] * inv);
    o4.y = f2bf(e[i * 4 + 1] * inv);
    o4.z = f2bf(e[i * 4 + 2] * inv);
    o4.w = f2bf(e[i * 4 + 3] * inv);
    reinterpret_cast<ushort4*>(pr)[t + i * 256] = o4;
  }
}

// ---------------------------------------------------------------------------
extern "C" void kernel_launch(void* const* d_in, const int* in_sizes, int n_in,
                              void* d_out, int out_size, void* d_ws, size_t ws_size,
                              hipStream_t stream) {
  const float* emb  = (const float*)d_in[0];
  const float* mask = (const float*)d_in[1];
  const float* wq   = (const float*)d_in[2];
  const float* wk   = (const float*)d_in[3];
  const float* wv   = (const float*)d_in[4];
  float* out = (float*)d_out;
  char* ws = (char*)d_ws;

  // Workspace: rounds 4-11 layout (106,954,752, proven) plus optional maskT
  // [4096][4096] bf16 (need2 = 140,509,184; proven rounds 9-11).
  const size_t need = 106954752;
  const size_t need2 = need + (size_t)S_LEN * S_LEN * 2;
  if (ws_size < need) return;
  const bool useT = (ws_size >= need2);

  unsigned short* Eh  = (unsigned short*)(ws);
  unsigned short* El  = (unsigned short*)(ws + 8388608);
  unsigned short* QMh = (unsigned short*)(ws + 16777216);
  unsigned short* QMl = (unsigned short*)(ws + 25165824);
  unsigned short* Vt  = QMh;  // alias, live only after scores
  unsigned short* MtH = (unsigned short*)(ws + 33554432);
  unsigned short* MtL = (unsigned short*)(ws + 35651584);
  unsigned short* Wvt = (unsigned short*)(ws + 37748736);
  float* scores       = (float*)(ws + 39845888);
  unsigned short* WqH = (unsigned short*)(ws + 39845888);
  unsigned short* WqL = (unsigned short*)(ws + 39845888 + 2097152);
  unsigned short* WkH = (unsigned short*)(ws + 39845888 + 4194304);
  unsigned short* WkL = (unsigned short*)(ws + 39845888 + 6291456);
  unsigned short* maskT = useT ? (unsigned short*)(ws + need) : nullptr;

  // ---- once: split weights, transpose Wv (+mask), precompute Mt -----------
  split32<<<1024, 256, 0, stream>>>(wq, WqH, WqL);
  split32<<<1024, 256, 0, stream>>>(wk, WkH, WkL);
  prep_wv<<<dim3(32, 32), dim3(32, 8), 0, stream>>>(wv, Wvt);
  if (useT)
    prep_maskT<<<dim3(128, 128), dim3(32, 8), 0, stream>>>(mask, maskT);
  gemm_bt<1, 0, 1><<<dim3(8, 8), 256, 0, stream>>>(
      WkH, WkL, 1024, WqH, WqL, 1024, (void*)MtH, 1024, MtL, 32);

  for (int b = 0; b < 2; ++b) {
    const float* embb = emb + (size_t)b * 4096 * 1024;
    float* outb = out + (size_t)b * 4096 * 1024;

    // 1) split embeddings into bf16 hi/lo
    split32<<<4096, 256, 0, stream>>>(embb, Eh, El);
    // 2) QM = E*Mt^T (SPLIT, 128^2 engine), hi/lo store
    gemm_bt<1, 0, 1><<<dim3(32, 8), 256, 0, stream>>>(
        Eh, El, 1024, MtH, MtL, 1024, (void*)QMh, 1024, QMl, 32);
    // 3) scores = (QM * E^T)/32 + mask_filled^T  (256^2 8-wave engine)
    gemm8s<<<dim3(16, 16), 512, 0, stream>>>(
        QMh, QMl, 1024, Eh, El, 1024, scores, 4096, mask, maskT, 0.03125f, 32);
    // 4) Vt = Wvt * E^T (plain bf16, BK=64; overwrites dead QMh region)
    gemm_bt<0, 2, 2><<<dim3(8, 32), 256, 0, stream>>>(
        Wvt, nullptr, 1024, Eh, nullptr, 1024, (void*)Vt, 4096, nullptr, 32);
    // 5) row softmax -> P bf16, in place (row stride 8192 ushorts)
    softmax_rows<<<4096, 256, 0, stream>>>(scores);
    // 6) out = P @ V (plain, BK=64), fp32 store
    gemm_bt<0, 3, 2><<<dim3(32, 8), 256, 0, stream>>>(
        (unsigned short*)scores, nullptr, 8192, Vt, nullptr, 4096,
        (void*)outb, 1024, nullptr, 128);
  }
}

// Round 13
// 517.410 us; speedup vs baseline: 1.1637x; 1.1062x over previous
//
#include <hip/hip_runtime.h>

// Self-attention B=2, S=4096, D=1024, fp32 in/out.
//
// Round-13: TLP for the grid-starved 128^2 dispatches.
//   QM/Vt/PV ran 128^2 tiles at grid=256 = 1 block/CU (4 waves = 1/SIMD):
//   every staging drain fully exposed (latency-bound, Occupancy ~20%).
//   N=1024 forbids the 256^2 structure (grid would be 64). Lever: 64x128
//   M-tiles -> grid 512 = 2 blocks/CU; cross-block overlap hides drains.
//   gemm_bt gains template<BM> (64|128); QM/Vt/PV use BM=64.
//   gemm8s (scores) UNCHANGED -- control at 96.6us.
// Algebra unchanged: QM trick + split-bf16 {hh,hl,lh}; XOR-swizzled LDS;
// bf16 maskT epilogue; KU=2 on plain-bf16 kernels.

#define S_LEN 4096

typedef __bf16 bf16x8 __attribute__((ext_vector_type(8)));
typedef float f32x4 __attribute__((ext_vector_type(4)));

__device__ __forceinline__ unsigned short f2bf(float x) {
  unsigned u = __float_as_uint(x);
  unsigned r = u + 0x7fffu + ((u >> 16) & 1u);  // round-to-nearest-even
  return (unsigned short)(r >> 16);
}
__device__ __forceinline__ float bf2f(unsigned short h) {
  return __uint_as_float(((unsigned)h) << 16);
}

__device__ __forceinline__ void gl_lds16(const void* g, void* l) {
  __builtin_amdgcn_global_load_lds(
      (const __attribute__((address_space(1))) void*)g,
      (__attribute__((address_space(3))) void*)l, 16, 0, 0);
}

// ---------------------------------------------------------------------------
// split32: fp32 -> (hi, lo) bf16 pair, elementwise, float4-vectorized.
__launch_bounds__(256)
__global__ void split32(const float* __restrict__ e,
                        unsigned short* __restrict__ Eh,
                        unsigned short* __restrict__ El) {
  int i = blockIdx.x * 256 + threadIdx.x;  // float4 index
  float4 v = reinterpret_cast<const float4*>(e)[i];
  ushort4 h, l;
  h.x = f2bf(v.x); l.x = f2bf(v.x - bf2f(h.x));
  h.y = f2bf(v.y); l.y = f2bf(v.y - bf2f(h.y));
  h.z = f2bf(v.z); l.z = f2bf(v.z - bf2f(h.z));
  h.w = f2bf(v.w); l.w = f2bf(v.w - bf2f(h.w));
  reinterpret_cast<ushort4*>(Eh)[i] = h;
  reinterpret_cast<ushort4*>(El)[i] = l;
}

// ---------------------------------------------------------------------------
// prep_wv: Wv[d][e] -> Wvt[e][d] plain bf16. 32x32 LDS transpose.
__launch_bounds__(256)
__global__ void prep_wv(const float* __restrict__ wv, unsigned short* __restrict__ Wvt) {
  __shared__ float tile[32][33];
  const int bx = blockIdx.x * 32;
  const int by = blockIdx.y * 32;
  const int tx = threadIdx.x;
  const int ty = threadIdx.y;
#pragma unroll
  for (int j = 0; j < 4; ++j)
    tile[ty + j * 8][tx] = wv[(long)(by + ty + j * 8) * 1024 + bx + tx];
  __syncthreads();
#pragma unroll
  for (int j = 0; j < 4; ++j) {
    float v = tile[tx][ty + j * 8];
    Wvt[(long)(bx + ty + j * 8) * 1024 + by + tx] = f2bf(v);
  }
}

// ---------------------------------------------------------------------------
// prep_maskT: maskT[q][k] = bf16(mask_filled[k][q]), mask==0 -> -inf (0xFF80).
__launch_bounds__(256)
__global__ void prep_maskT(const float* __restrict__ mask,
                           unsigned short* __restrict__ maskT) {
  __shared__ float tile[32][33];
  const int bx = blockIdx.x * 32;  // q block
  const int by = blockIdx.y * 32;  // k block
  const int tx = threadIdx.x;
  const int ty = threadIdx.y;
#pragma unroll
  for (int j = 0; j < 4; ++j)
    tile[ty + j * 8][tx] = mask[(long)(by + ty + j * 8) * S_LEN + bx + tx];
  __syncthreads();
#pragma unroll
  for (int j = 0; j < 4; ++j) {
    float v = tile[tx][ty + j * 8];  // = mask[by+tx][bx+ty+j*8]
    unsigned short u = (v == 0.0f) ? (unsigned short)0xFF80 : f2bf(v);
    maskT[(long)(bx + ty + j * 8) * S_LEN + by + tx] = u;
  }
}

// ---------------------------------------------------------------------------
// BMx128 engine: NT GEMM with XOR-swizzled LDS. KU = K-unroll, BM in {64,128}.
// 4 waves: wave tile (BM/2) x 64.  MODE 0: hi/lo pair  MODE 2: bf16  MODE 3: f32.
template <int SPLIT, int MODE, int KU, int BM>
__launch_bounds__(256)
__global__ void gemm_bt(const unsigned short* __restrict__ Ah,
                        const unsigned short* __restrict__ Al, int lda,
                        const unsigned short* __restrict__ Bh,
                        const unsigned short* __restrict__ Bl, int ldb,
                        void* __restrict__ Cp, int ldc,
                        unsigned short* __restrict__ C2, int kIters) {
  constexpr int NMI = BM / 32;        // fragment rows per wave (4 or 2)
  __shared__ unsigned short lAh[KU * BM * 32];
  __shared__ unsigned short lBh[KU * 128 * 32];
  __shared__ unsigned short lAl[SPLIT ? KU * BM * 32 : 8];
  __shared__ unsigned short lBl[SPLIT ? KU * 128 * 32 : 8];

  const int t = threadIdx.x;
  const int w = t >> 6;
  const int lane = t & 63;
  const int g = lane >> 4;
  const int r = lane & 15;
  const int wm = (w >> 1) * (BM / 2);
  const int wn = (w & 1) * 64;
  const long bm = (long)blockIdx.x * BM;
  const long bn = (long)blockIdx.y * 128;

  f32x4 acc[NMI][4];
  const f32x4 vzero = {0.f, 0.f, 0.f, 0.f};
#pragma unroll
  for (int mi = 0; mi < NMI; ++mi)
#pragma unroll
    for (int ni = 0; ni < 4; ++ni) acc[mi][ni] = vzero;

  const int outer = kIters / KU;
  for (int kt = 0; kt < outer; ++kt) {
    __syncthreads();
    const long kbase = (long)kt * 32 * KU;
#pragma unroll
    for (int u = 0; u < KU; ++u) {
      // A tile: BM*4 granules (1 or 2 passes of 256 threads)
#pragma unroll
      for (int i = 0; i < BM * 4 / 256; ++i) {
        int s = i * 256 + t;
        int row = s >> 2;
        int ko = (s & 3) ^ ((row >> 1) & 3);
        long goffA = (bm + row) * (long)lda + kbase + u * 32 + ko * 8;
        int lbase = u * (BM * 32) + i * 2048 + w * 512;
        gl_lds16(Ah + goffA, lAh + lbase);
        if constexpr (SPLIT) gl_lds16(Al + goffA, lAl + lbase);
      }
      // B tile: 512 granules (2 passes)
#pragma unroll
      for (int i = 0; i < 2; ++i) {
        int s = i * 256 + t;
        int row = s >> 2;
        int ko = (s & 3) ^ ((row >> 1) & 3);
        long goffB = (bn + row) * (long)ldb + kbase + u * 32 + ko * 8;
        int lbase = u * 4096 + i * 2048 + w * 512;
        gl_lds16(Bh + goffB, lBh + lbase);
        if constexpr (SPLIT) gl_lds16(Bl + goffB, lBl + lbase);
      }
    }
    __syncthreads();

#pragma unroll
    for (int u = 0; u < KU; ++u) {
      bf16x8 af[NMI], bfh[4], af2[NMI], bf2v[4];
#pragma unroll
      for (int mi = 0; mi < NMI; ++mi) {
        int rowa = wm + mi * 16 + r;
        int o = u * (BM * 32) + rowa * 32 + ((g ^ ((rowa >> 1) & 3)) * 8);
        af[mi] = *reinterpret_cast<const bf16x8*>(&lAh[o]);
        if constexpr (SPLIT)
          af2[mi] = *reinterpret_cast<const bf16x8*>(&lAl[o]);
      }
#pragma unroll
      for (int ni = 0; ni < 4; ++ni) {
        int rowb = wn + ni * 16 + r;
        int o = u * 4096 + rowb * 32 + ((g ^ ((rowb >> 1) & 3)) * 8);
        bfh[ni] = *reinterpret_cast<const bf16x8*>(&lBh[o]);
        if constexpr (SPLIT)
          bf2v[ni] = *reinterpret_cast<const bf16x8*>(&lBl[o]);
      }
#pragma unroll
      for (int mi = 0; mi < NMI; ++mi)
#pragma unroll
        for (int ni = 0; ni < 4; ++ni) {
          acc[mi][ni] = __builtin_amdgcn_mfma_f32_16x16x32_bf16(af[mi], bfh[ni], acc[mi][ni], 0, 0, 0);
          if constexpr (SPLIT) {
            acc[mi][ni] = __builtin_amdgcn_mfma_f32_16x16x32_bf16(af[mi], bf2v[ni], acc[mi][ni], 0, 0, 0);
            acc[mi][ni] = __builtin_amdgcn_mfma_f32_16x16x32_bf16(af2[mi], bfh[ni], acc[mi][ni], 0, 0, 0);
          }
        }
    }
  }

#pragma unroll
  for (int mi = 0; mi < NMI; ++mi) {
#pragma unroll
    for (int ni = 0; ni < 4; ++ni) {
      long row0 = bm + wm + mi * 16 + g * 4;
      long col = bn + wn + ni * 16 + r;
#pragma unroll
      for (int q = 0; q < 4; ++q) {
        float v = acc[mi][ni][q];
        long row = row0 + q;
        if constexpr (MODE == 0) {
          unsigned short h = f2bf(v);
          ((unsigned short*)Cp)[row * (long)ldc + col] = h;
          C2[row * (long)ldc + col] = f2bf(v - bf2f(h));
        } else if constexpr (MODE == 2) {
          ((unsigned short*)Cp)[row * (long)ldc + col] = f2bf(v);
        } else {
          ((float*)Cp)[row * (long)ldc + col] = v;
        }
      }
    }
  }
}

// ---------------------------------------------------------------------------
// Scores kernel (round-12-proven): 256^2, 8 waves (2M x 4N), BK=32,
// 2-stage LDS dbuf, 4 phases/K-step, staging A@p0 B@p1.
__launch_bounds__(512, 2)
__global__ void gemm8s(const unsigned short* __restrict__ Ah,
                       const unsigned short* __restrict__ Al, int lda,
                       const unsigned short* __restrict__ Bh,
                       const unsigned short* __restrict__ Bl, int ldb,
                       float* __restrict__ C, int ldc,
                       const float* __restrict__ mask,
                       const unsigned short* __restrict__ maskT,
                       float scale, int nkt) {
  __shared__ __align__(16) unsigned short lds[4][2][8192];

  const int t = threadIdx.x;          // 0..511
  const int w = t >> 6;               // wave 0..7
  const int lane = t & 63;
  const int g = lane >> 4;
  const int r = lane & 15;
  const int wr = w >> 2;              // 0..1  (M)
  const int wc = w & 3;               // 0..3  (N)
  const long bm = (long)blockIdx.x * 256;
  const long bn = (long)blockIdx.y * 256;

  const int row0 = t >> 2;
  const int ko = (t & 3) ^ ((t >> 3) & 3);
  const unsigned short* pAh = Ah + (bm + row0) * (long)lda + ko * 8;
  const unsigned short* pAl = Al + (bm + row0) * (long)lda + ko * 8;
  const unsigned short* pBh = Bh + (bn + row0) * (long)ldb + ko * 8;
  const unsigned short* pBl = Bl + (bn + row0) * (long)ldb + ko * 8;

  f32x4 acc[8][4];
  const f32x4 vzero = {0.f, 0.f, 0.f, 0.f};
#pragma unroll
  for (int mi = 0; mi < 8; ++mi)
#pragma unroll
    for (int ni = 0; ni < 4; ++ni) acc[mi][ni] = vzero;

  // Prologue: stage K-step 0 into buf 0.
#pragma unroll
  for (int T = 0; T < 4; ++T) {
    const unsigned short* sp = (T == 0) ? pAh : (T == 1) ? pAl : (T == 2) ? pBh : pBl;
    long ld = (T < 2) ? lda : ldb;
    gl_lds16(sp, &lds[T][0][w * 512]);
    gl_lds16(sp + 128 * ld, &lds[T][0][4096 + w * 512]);
  }
  asm volatile("s_waitcnt vmcnt(0)" ::: "memory");
  __syncthreads();

  for (int kt = 0; kt < nkt; ++kt) {
    const int cb = kt & 1, nb = cb ^ 1;
    const bool stg = (kt < nkt - 1);
    bf16x8 bh[4], bl[4];
#pragma unroll
    for (int p = 0; p < 4; ++p) {
      if (p == 0) {
#pragma unroll
        for (int ni = 0; ni < 4; ++ni) {
          int rowb = wc * 64 + ni * 16 + r;
          int o = rowb * 32 + ((g ^ ((rowb >> 1) & 3)) * 8);
          bh[ni] = *reinterpret_cast<const bf16x8*>(&lds[2][cb][o]);
          bl[ni] = *reinterpret_cast<const bf16x8*>(&lds[3][cb][o]);
        }
      }
      bf16x8 ah[2], al[2];
#pragma unroll
      for (int i = 0; i < 2; ++i) {
        int rowa = wr * 128 + (2 * p + i) * 16 + r;
        int o = rowa * 32 + ((g ^ ((rowa >> 1) & 3)) * 8);
        ah[i] = *reinterpret_cast<const bf16x8*>(&lds[0][cb][o]);
        al[i] = *reinterpret_cast<const bf16x8*>(&lds[1][cb][o]);
      }
      // Staging: A tiles at phase 0, B tiles at phase 1 (round-9-proven).
      if (stg && p == 0) {
        gl_lds16(pAh + 32, &lds[0][nb][w * 512]);
        gl_lds16(pAh + 32 + 128 * (long)lda, &lds[0][nb][4096 + w * 512]);
        gl_lds16(pAl + 32, &lds[1][nb][w * 512]);
        gl_lds16(pAl + 32 + 128 * (long)lda, &lds[1][nb][4096 + w * 512]);
      }
      if (stg && p == 1) {
        gl_lds16(pBh + 32, &lds[2][nb][w * 512]);
        gl_lds16(pBh + 32 + 128 * (long)ldb, &lds[2][nb][4096 + w * 512]);
        gl_lds16(pBl + 32, &lds[3][nb][w * 512]);
        gl_lds16(pBl + 32 + 128 * (long)ldb, &lds[3][nb][4096 + w * 512]);
      }
      __builtin_amdgcn_s_barrier();
      __builtin_amdgcn_s_setprio(1);
#pragma unroll
      for (int i = 0; i < 2; ++i) {
        const int mi = 2 * p + i;
#pragma unroll
        for (int ni = 0; ni < 4; ++ni) {
          acc[mi][ni] = __builtin_amdgcn_mfma_f32_16x16x32_bf16(ah[i], bh[ni], acc[mi][ni], 0, 0, 0);
          acc[mi][ni] = __builtin_amdgcn_mfma_f32_16x16x32_bf16(ah[i], bl[ni], acc[mi][ni], 0, 0, 0);
          acc[mi][ni] = __builtin_amdgcn_mfma_f32_16x16x32_bf16(al[i], bh[ni], acc[mi][ni], 0, 0, 0);
        }
      }
      __builtin_amdgcn_s_setprio(0);
      if (p < 3) __builtin_amdgcn_s_barrier();
    }
    asm volatile("s_waitcnt vmcnt(0)" ::: "memory");
    __syncthreads();
    pAh += 32; pAl += 32; pBh += 32; pBl += 32;
  }

  // Epilogue: scores = acc*scale + mask_filled^T.
  if (maskT) {
#pragma unroll
    for (int mi = 0; mi < 8; ++mi) {
#pragma unroll
      for (int ni = 0; ni < 4; ++ni) {
        long row0q = bm + wr * 128 + mi * 16 + g * 4;
        long col = bn + wc * 64 + ni * 16 + r;
#pragma unroll
        for (int q = 0; q < 4; ++q) {
          long row = row0q + q;
          float mv = bf2f(maskT[row * (long)S_LEN + col]);
          C[row * (long)ldc + col] = acc[mi][ni][q] * scale + mv;
        }
      }
    }
  } else {
#pragma unroll
    for (int mi = 0; mi < 8; ++mi) {
#pragma unroll
      for (int ni = 0; ni < 4; ++ni) {
        long row0q = bm + wr * 128 + mi * 16 + g * 4;
        long col = bn + wc * 64 + ni * 16 + r;
#pragma unroll
        for (int q = 0; q < 4; ++q) {
          long row = row0q + q;
          float mv = mask[col * (long)S_LEN + row];
          float v = acc[mi][ni][q] * scale;
          v = (mv == 0.0f) ? -__builtin_inff() : (v + mv);
          C[row * (long)ldc + col] = v;
        }
      }
    }
  }
}

// ---------------------------------------------------------------------------
// Row softmax, IN PLACE: fp32 row -> bf16 P in the same storage.
__launch_bounds__(256)
__global__ void softmax_rows(float* __restrict__ Sc) {
  const long row = blockIdx.x;
  float* sr = Sc + row * (long)S_LEN;
  unsigned short* pr = (unsigned short*)sr;
  const int t = threadIdx.x;
  const int lane = t & 63, wid = t >> 6;

  float4 x[4];
  float m = -3.0e38f;
#pragma unroll
  for (int i = 0; i < 4; ++i) {
    x[i] = reinterpret_cast<const float4*>(sr)[t + i * 256];
    m = fmaxf(m, fmaxf(fmaxf(x[i].x, x[i].y), fmaxf(x[i].z, x[i].w)));
  }
#pragma unroll
  for (int o = 32; o; o >>= 1) m = fmaxf(m, __shfl_xor(m, o));
  __shared__ float redm[4];
  __shared__ float reds[4];
  if (lane == 0) redm[wid] = m;
  __syncthreads();
  m = fmaxf(fmaxf(redm[0], redm[1]), fmaxf(redm[2], redm[3]));

  float e[16];
  float s = 0.f;
#pragma unroll
  for (int i = 0; i < 4; ++i) {
    e[i * 4 + 0] = __expf(x[i].x - m);
    e[i * 4 + 1] = __expf(x[i].y - m);
    e[i * 4 + 2] = __expf(x[i].z - m);
    e[i * 4 + 3] = __expf(x[i].w - m);
    s += e[i * 4 + 0] + e[i * 4 + 1] + e[i * 4 + 2] + e[i * 4 + 3];
  }
#pragma unroll
  for (int o = 32; o; o >>= 1) s += __shfl_xor(s, o);
  if (lane == 0) reds[wid] = s;
  __syncthreads();
  s = reds[0] + reds[1] + reds[2] + reds[3];
  float inv = 1.0f / s;
#pragma unroll
  for (int i = 0; i < 4; ++i) {
    ushort4 o4;
    o4.x = f2bf(e[i * 4 + 0] * inv);
    o4.y = f2bf(e[i * 4 + 1] * inv);
    o4.z = f2bf(e[i * 4 + 2] * inv);
    o4.w = f2bf(e[i * 4 + 3] * inv);
    reinterpret_cast<ushort4*>(pr)[t + i * 256] = o4;
  }
}

// ---------------------------------------------------------------------------
extern "C" void kernel_launch(void* const* d_in, const int* in_sizes, int n_in,
                              void* d_out, int out_size, void* d_ws, size_t ws_size,
                              hipStream_t stream) {
  const float* emb  = (const float*)d_in[0];
  const float* mask = (const float*)d_in[1];
  const float* wq   = (const float*)d_in[2];
  const float* wk   = (const float*)d_in[3];
  const float* wv   = (const float*)d_in[4];
  float* out = (float*)d_out;
  char* ws = (char*)d_ws;

  // Workspace: rounds 4-12 layout (106,954,752, proven) plus optional maskT
  // [4096][4096] bf16 (need2 = 140,509,184; proven rounds 9-12).
  const size_t need = 106954752;
  const size_t need2 = need + (size_t)S_LEN * S_LEN * 2;
  if (ws_size < need) return;
  const bool useT = (ws_size >= need2);

  unsigned short* Eh  = (unsigned short*)(ws);
  unsigned short* El  = (unsigned short*)(ws + 8388608);
  unsigned short* QMh = (unsigned short*)(ws + 16777216);
  unsigned short* QMl = (unsigned short*)(ws + 25165824);
  unsigned short* Vt  = QMh;  // alias, live only after scores
  unsigned short* MtH = (unsigned short*)(ws + 33554432);
  unsigned short* MtL = (unsigned short*)(ws + 35651584);
  unsigned short* Wvt = (unsigned short*)(ws + 37748736);
  float* scores       = (float*)(ws + 39845888);
  unsigned short* WqH = (unsigned short*)(ws + 39845888);
  unsigned short* WqL = (unsigned short*)(ws + 39845888 + 2097152);
  unsigned short* WkH = (unsigned short*)(ws + 39845888 + 4194304);
  unsigned short* WkL = (unsigned short*)(ws + 39845888 + 6291456);
  unsigned short* maskT = useT ? (unsigned short*)(ws + need) : nullptr;

  // ---- once: split weights, transpose Wv (+mask), precompute Mt -----------
  split32<<<1024, 256, 0, stream>>>(wq, WqH, WqL);
  split32<<<1024, 256, 0, stream>>>(wk, WkH, WkL);
  prep_wv<<<dim3(32, 32), dim3(32, 8), 0, stream>>>(wv, Wvt);
  if (useT)
    prep_maskT<<<dim3(128, 128), dim3(32, 8), 0, stream>>>(mask, maskT);
  gemm_bt<1, 0, 1, 128><<<dim3(8, 8), 256, 0, stream>>>(
      WkH, WkL, 1024, WqH, WqL, 1024, (void*)MtH, 1024, MtL, 32);

  for (int b = 0; b < 2; ++b) {
    const float* embb = emb + (size_t)b * 4096 * 1024;
    float* outb = out + (size_t)b * 4096 * 1024;

    // 1) split embeddings into bf16 hi/lo
    split32<<<4096, 256, 0, stream>>>(embb, Eh, El);
    // 2) QM = E*Mt^T (SPLIT, BM=64 -> grid 512 = 2 blocks/CU), hi/lo store
    gemm_bt<1, 0, 1, 64><<<dim3(64, 8), 256, 0, stream>>>(
        Eh, El, 1024, MtH, MtL, 1024, (void*)QMh, 1024, QMl, 32);
    // 3) scores = (QM * E^T)/32 + mask_filled^T  (256^2 8-wave engine)
    gemm8s<<<dim3(16, 16), 512, 0, stream>>>(
        QMh, QMl, 1024, Eh, El, 1024, scores, 4096, mask, maskT, 0.03125f, 32);
    // 4) Vt = Wvt * E^T (plain bf16, BK=64, BM=64 -> grid 512)
    gemm_bt<0, 2, 2, 64><<<dim3(16, 32), 256, 0, stream>>>(
        Wvt, nullptr, 1024, Eh, nullptr, 1024, (void*)Vt, 4096, nullptr, 32);
    // 5) row softmax -> P bf16, in place (row stride 8192 ushorts)
    softmax_rows<<<4096, 256, 0, stream>>>(scores);
    // 6) out = P @ V (plain, BK=64, BM=64 -> grid 512), fp32 store
    gemm_bt<0, 3, 2, 64><<<dim3(64, 8), 256, 0, stream>>>(
        (unsigned short*)scores, nullptr, 8192, Vt, nullptr, 4096,
        (void*)outb, 1024, nullptr, 128);
  }
}

// Round 15
// 497.657 us; speedup vs baseline: 1.2099x; 1.0397x over previous
//
#include <hip/hip_runtime.h>

// Self-attention B=2, S=4096, D=1024, fp32 in/out.
//
// Round-15: fix round-14's workspace clobber.
//   Dense P was 33.5MB placed over "Eh+El" (only 16.8MB) -> its upper half
//   overlaid QMh/QMl, and QMh aliases Vt -> PV read destroyed V (absmax 169).
//   REVERT softmax to the round-13-proven IN-PLACE form (bf16 P over fp32
//   scores rows, row stride 8192 ushorts). KEEP round-14's sound changes:
//   * KU=2 for SPLIT kernels (QM, Mt) with the lAl/lBl KU-scaling fix.
//   * merged wq/wk split (one dispatch).
// Algebra unchanged: QM trick + split-bf16 {hh,hl,lh}; XOR-swizzled LDS;
// bf16 maskT epilogue; BM=64 TLP tiles; gemm8s = round-12 control.

#define S_LEN 4096

typedef __bf16 bf16x8 __attribute__((ext_vector_type(8)));
typedef float f32x4 __attribute__((ext_vector_type(4)));

__device__ __forceinline__ unsigned short f2bf(float x) {
  unsigned u = __float_as_uint(x);
  unsigned r = u + 0x7fffu + ((u >> 16) & 1u);  // round-to-nearest-even
  return (unsigned short)(r >> 16);
}
__device__ __forceinline__ float bf2f(unsigned short h) {
  return __uint_as_float(((unsigned)h) << 16);
}

__device__ __forceinline__ void gl_lds16(const void* g, void* l) {
  __builtin_amdgcn_global_load_lds(
      (const __attribute__((address_space(1))) void*)g,
      (__attribute__((address_space(3))) void*)l, 16, 0, 0);
}

// ---------------------------------------------------------------------------
// split32: fp32 -> (hi, lo) bf16 pair, elementwise, float4-vectorized.
__launch_bounds__(256)
__global__ void split32(const float* __restrict__ e,
                        unsigned short* __restrict__ Eh,
                        unsigned short* __restrict__ El) {
  int i = blockIdx.x * 256 + threadIdx.x;  // float4 index
  float4 v = reinterpret_cast<const float4*>(e)[i];
  ushort4 h, l;
  h.x = f2bf(v.x); l.x = f2bf(v.x - bf2f(h.x));
  h.y = f2bf(v.y); l.y = f2bf(v.y - bf2f(h.y));
  h.z = f2bf(v.z); l.z = f2bf(v.z - bf2f(h.z));
  h.w = f2bf(v.w); l.w = f2bf(v.w - bf2f(h.w));
  reinterpret_cast<ushort4*>(Eh)[i] = h;
  reinterpret_cast<ushort4*>(El)[i] = l;
}

// splitW: wq and wk hi/lo split in one dispatch (grid 2048; 262144 float4 each).
__launch_bounds__(256)
__global__ void splitW(const float* __restrict__ wq, const float* __restrict__ wk,
                       unsigned short* __restrict__ WqH, unsigned short* __restrict__ WqL,
                       unsigned short* __restrict__ WkH, unsigned short* __restrict__ WkL) {
  int i = blockIdx.x * 256 + threadIdx.x;
  const bool isQ = (i < 262144);
  const float* s = isQ ? wq : wk;
  unsigned short* H = isQ ? WqH : WkH;
  unsigned short* L = isQ ? WqL : WkL;
  int j = isQ ? i : i - 262144;
  float4 v = reinterpret_cast<const float4*>(s)[j];
  ushort4 h, l;
  h.x = f2bf(v.x); l.x = f2bf(v.x - bf2f(h.x));
  h.y = f2bf(v.y); l.y = f2bf(v.y - bf2f(h.y));
  h.z = f2bf(v.z); l.z = f2bf(v.z - bf2f(h.z));
  h.w = f2bf(v.w); l.w = f2bf(v.w - bf2f(h.w));
  reinterpret_cast<ushort4*>(H)[j] = h;
  reinterpret_cast<ushort4*>(L)[j] = l;
}

// ---------------------------------------------------------------------------
// prep_wv: Wv[d][e] -> Wvt[e][d] plain bf16. 32x32 LDS transpose.
__launch_bounds__(256)
__global__ void prep_wv(const float* __restrict__ wv, unsigned short* __restrict__ Wvt) {
  __shared__ float tile[32][33];
  const int bx = blockIdx.x * 32;
  const int by = blockIdx.y * 32;
  const int tx = threadIdx.x;
  const int ty = threadIdx.y;
#pragma unroll
  for (int j = 0; j < 4; ++j)
    tile[ty + j * 8][tx] = wv[(long)(by + ty + j * 8) * 1024 + bx + tx];
  __syncthreads();
#pragma unroll
  for (int j = 0; j < 4; ++j) {
    float v = tile[tx][ty + j * 8];
    Wvt[(long)(bx + ty + j * 8) * 1024 + by + tx] = f2bf(v);
  }
}

// ---------------------------------------------------------------------------
// prep_maskT: maskT[q][k] = bf16(mask_filled[k][q]), mask==0 -> -inf (0xFF80).
__launch_bounds__(256)
__global__ void prep_maskT(const float* __restrict__ mask,
                           unsigned short* __restrict__ maskT) {
  __shared__ float tile[32][33];
  const int bx = blockIdx.x * 32;  // q block
  const int by = blockIdx.y * 32;  // k block
  const int tx = threadIdx.x;
  const int ty = threadIdx.y;
#pragma unroll
  for (int j = 0; j < 4; ++j)
    tile[ty + j * 8][tx] = mask[(long)(by + ty + j * 8) * S_LEN + bx + tx];
  __syncthreads();
#pragma unroll
  for (int j = 0; j < 4; ++j) {
    float v = tile[tx][ty + j * 8];  // = mask[by+tx][bx+ty+j*8]
    unsigned short u = (v == 0.0f) ? (unsigned short)0xFF80 : f2bf(v);
    maskT[(long)(bx + ty + j * 8) * S_LEN + by + tx] = u;
  }
}

// ---------------------------------------------------------------------------
// BMx128 engine: NT GEMM with XOR-swizzled LDS. KU = K-unroll, BM in {64,128}.
// 4 waves: wave tile (BM/2) x 64.  MODE 0: hi/lo pair  MODE 2: bf16  MODE 3: f32.
template <int SPLIT, int MODE, int KU, int BM>
__launch_bounds__(256)
__global__ void gemm_bt(const unsigned short* __restrict__ Ah,
                        const unsigned short* __restrict__ Al, int lda,
                        const unsigned short* __restrict__ Bh,
                        const unsigned short* __restrict__ Bl, int ldb,
                        void* __restrict__ Cp, int ldc,
                        unsigned short* __restrict__ C2, int kIters) {
  constexpr int NMI = BM / 32;        // fragment rows per wave (4 or 2)
  __shared__ unsigned short lAh[KU * BM * 32];
  __shared__ unsigned short lBh[KU * 128 * 32];
  __shared__ unsigned short lAl[SPLIT ? KU * BM * 32 : 8];   // KU-scaled
  __shared__ unsigned short lBl[SPLIT ? KU * 128 * 32 : 8];

  const int t = threadIdx.x;
  const int w = t >> 6;
  const int lane = t & 63;
  const int g = lane >> 4;
  const int r = lane & 15;
  const int wm = (w >> 1) * (BM / 2);
  const int wn = (w & 1) * 64;
  const long bm = (long)blockIdx.x * BM;
  const long bn = (long)blockIdx.y * 128;

  f32x4 acc[NMI][4];
  const f32x4 vzero = {0.f, 0.f, 0.f, 0.f};
#pragma unroll
  for (int mi = 0; mi < NMI; ++mi)
#pragma unroll
    for (int ni = 0; ni < 4; ++ni) acc[mi][ni] = vzero;

  const int outer = kIters / KU;
  for (int kt = 0; kt < outer; ++kt) {
    __syncthreads();
    const long kbase = (long)kt * 32 * KU;
#pragma unroll
    for (int u = 0; u < KU; ++u) {
      // A tile: BM*4 granules (1 or 2 passes of 256 threads)
#pragma unroll
      for (int i = 0; i < BM * 4 / 256; ++i) {
        int s = i * 256 + t;
        int row = s >> 2;
        int ko = (s & 3) ^ ((row >> 1) & 3);
        long goffA = (bm + row) * (long)lda + kbase + u * 32 + ko * 8;
        int lbase = u * (BM * 32) + i * 2048 + w * 512;
        gl_lds16(Ah + goffA, lAh + lbase);
        if constexpr (SPLIT) gl_lds16(Al + goffA, lAl + lbase);
      }
      // B tile: 512 granules (2 passes)
#pragma unroll
      for (int i = 0; i < 2; ++i) {
        int s = i * 256 + t;
        int row = s >> 2;
        int ko = (s & 3) ^ ((row >> 1) & 3);
        long goffB = (bn + row) * (long)ldb + kbase + u * 32 + ko * 8;
        int lbase = u * 4096 + i * 2048 + w * 512;
        gl_lds16(Bh + goffB, lBh + lbase);
        if constexpr (SPLIT) gl_lds16(Bl + goffB, lBl + lbase);
      }
    }
    __syncthreads();

#pragma unroll
    for (int u = 0; u < KU; ++u) {
      bf16x8 af[NMI], bfh[4], af2[NMI], bf2v[4];
#pragma unroll
      for (int mi = 0; mi < NMI; ++mi) {
        int rowa = wm + mi * 16 + r;
        int o = u * (BM * 32) + rowa * 32 + ((g ^ ((rowa >> 1) & 3)) * 8);
        af[mi] = *reinterpret_cast<const bf16x8*>(&lAh[o]);
        if constexpr (SPLIT)
          af2[mi] = *reinterpret_cast<const bf16x8*>(&lAl[o]);
      }
#pragma unroll
      for (int ni = 0; ni < 4; ++ni) {
        int rowb = wn + ni * 16 + r;
        int o = u * 4096 + rowb * 32 + ((g ^ ((rowb >> 1) & 3)) * 8);
        bfh[ni] = *reinterpret_cast<const bf16x8*>(&lBh[o]);
        if constexpr (SPLIT)
          bf2v[ni] = *reinterpret_cast<const bf16x8*>(&lBl[o]);
      }
#pragma unroll
      for (int mi = 0; mi < NMI; ++mi)
#pragma unroll
        for (int ni = 0; ni < 4; ++ni) {
          acc[mi][ni] = __builtin_amdgcn_mfma_f32_16x16x32_bf16(af[mi], bfh[ni], acc[mi][ni], 0, 0, 0);
          if constexpr (SPLIT) {
            acc[mi][ni] = __builtin_amdgcn_mfma_f32_16x16x32_bf16(af[mi], bf2v[ni], acc[mi][ni], 0, 0, 0);
            acc[mi][ni] = __builtin_amdgcn_mfma_f32_16x16x32_bf16(af2[mi], bfh[ni], acc[mi][ni], 0, 0, 0);
          }
        }
    }
  }

#pragma unroll
  for (int mi = 0; mi < NMI; ++mi) {
#pragma unroll
    for (int ni = 0; ni < 4; ++ni) {
      long row0 = bm + wm + mi * 16 + g * 4;
      long col = bn + wn + ni * 16 + r;
#pragma unroll
      for (int q = 0; q < 4; ++q) {
        float v = acc[mi][ni][q];
        long row = row0 + q;
        if constexpr (MODE == 0) {
          unsigned short h = f2bf(v);
          ((unsigned short*)Cp)[row * (long)ldc + col] = h;
          C2[row * (long)ldc + col] = f2bf(v - bf2f(h));
        } else if constexpr (MODE == 2) {
          ((unsigned short*)Cp)[row * (long)ldc + col] = f2bf(v);
        } else {
          ((float*)Cp)[row * (long)ldc + col] = v;
        }
      }
    }
  }
}

// ---------------------------------------------------------------------------
// Scores kernel (round-12-proven, UNCHANGED): 256^2, 8 waves (2M x 4N),
// BK=32, 2-stage LDS dbuf, 4 phases/K-step, staging A@p0 B@p1.
__launch_bounds__(512, 2)
__global__ void gemm8s(const unsigned short* __restrict__ Ah,
                       const unsigned short* __restrict__ Al, int lda,
                       const unsigned short* __restrict__ Bh,
                       const unsigned short* __restrict__ Bl, int ldb,
                       float* __restrict__ C, int ldc,
                       const float* __restrict__ mask,
                       const unsigned short* __restrict__ maskT,
                       float scale, int nkt) {
  __shared__ __align__(16) unsigned short lds[4][2][8192];

  const int t = threadIdx.x;          // 0..511
  const int w = t >> 6;               // wave 0..7
  const int lane = t & 63;
  const int g = lane >> 4;
  const int r = lane & 15;
  const int wr = w >> 2;              // 0..1  (M)
  const int wc = w & 3;               // 0..3  (N)
  const long bm = (long)blockIdx.x * 256;
  const long bn = (long)blockIdx.y * 256;

  const int row0 = t >> 2;
  const int ko = (t & 3) ^ ((t >> 3) & 3);
  const unsigned short* pAh = Ah + (bm + row0) * (long)lda + ko * 8;
  const unsigned short* pAl = Al + (bm + row0) * (long)lda + ko * 8;
  const unsigned short* pBh = Bh + (bn + row0) * (long)ldb + ko * 8;
  const unsigned short* pBl = Bl + (bn + row0) * (long)ldb + ko * 8;

  f32x4 acc[8][4];
  const f32x4 vzero = {0.f, 0.f, 0.f, 0.f};
#pragma unroll
  for (int mi = 0; mi < 8; ++mi)
#pragma unroll
    for (int ni = 0; ni < 4; ++ni) acc[mi][ni] = vzero;

  // Prologue: stage K-step 0 into buf 0.
#pragma unroll
  for (int T = 0; T < 4; ++T) {
    const unsigned short* sp = (T == 0) ? pAh : (T == 1) ? pAl : (T == 2) ? pBh : pBl;
    long ld = (T < 2) ? lda : ldb;
    gl_lds16(sp, &lds[T][0][w * 512]);
    gl_lds16(sp + 128 * ld, &lds[T][0][4096 + w * 512]);
  }
  asm volatile("s_waitcnt vmcnt(0)" ::: "memory");
  __syncthreads();

  for (int kt = 0; kt < nkt; ++kt) {
    const int cb = kt & 1, nb = cb ^ 1;
    const bool stg = (kt < nkt - 1);
    bf16x8 bh[4], bl[4];
#pragma unroll
    for (int p = 0; p < 4; ++p) {
      if (p == 0) {
#pragma unroll
        for (int ni = 0; ni < 4; ++ni) {
          int rowb = wc * 64 + ni * 16 + r;
          int o = rowb * 32 + ((g ^ ((rowb >> 1) & 3)) * 8);
          bh[ni] = *reinterpret_cast<const bf16x8*>(&lds[2][cb][o]);
          bl[ni] = *reinterpret_cast<const bf16x8*>(&lds[3][cb][o]);
        }
      }
      bf16x8 ah[2], al[2];
#pragma unroll
      for (int i = 0; i < 2; ++i) {
        int rowa = wr * 128 + (2 * p + i) * 16 + r;
        int o = rowa * 32 + ((g ^ ((rowa >> 1) & 3)) * 8);
        ah[i] = *reinterpret_cast<const bf16x8*>(&lds[0][cb][o]);
        al[i] = *reinterpret_cast<const bf16x8*>(&lds[1][cb][o]);
      }
      // Staging: A tiles at phase 0, B tiles at phase 1 (round-9-proven).
      if (stg && p == 0) {
        gl_lds16(pAh + 32, &lds[0][nb][w * 512]);
        gl_lds16(pAh + 32 + 128 * (long)lda, &lds[0][nb][4096 + w * 512]);
        gl_lds16(pAl + 32, &lds[1][nb][w * 512]);
        gl_lds16(pAl + 32 + 128 * (long)lda, &lds[1][nb][4096 + w * 512]);
      }
      if (stg && p == 1) {
        gl_lds16(pBh + 32, &lds[2][nb][w * 512]);
        gl_lds16(pBh + 32 + 128 * (long)ldb, &lds[2][nb][4096 + w * 512]);
        gl_lds16(pBl + 32, &lds[3][nb][w * 512]);
        gl_lds16(pBl + 32 + 128 * (long)ldb, &lds[3][nb][4096 + w * 512]);
      }
      __builtin_amdgcn_s_barrier();
      __builtin_amdgcn_s_setprio(1);
#pragma unroll
      for (int i = 0; i < 2; ++i) {
        const int mi = 2 * p + i;
#pragma unroll
        for (int ni = 0; ni < 4; ++ni) {
          acc[mi][ni] = __builtin_amdgcn_mfma_f32_16x16x32_bf16(ah[i], bh[ni], acc[mi][ni], 0, 0, 0);
          acc[mi][ni] = __builtin_amdgcn_mfma_f32_16x16x32_bf16(ah[i], bl[ni], acc[mi][ni], 0, 0, 0);
          acc[mi][ni] = __builtin_amdgcn_mfma_f32_16x16x32_bf16(al[i], bh[ni], acc[mi][ni], 0, 0, 0);
        }
      }
      __builtin_amdgcn_s_setprio(0);
      if (p < 3) __builtin_amdgcn_s_barrier();
    }
    asm volatile("s_waitcnt vmcnt(0)" ::: "memory");
    __syncthreads();
    pAh += 32; pAl += 32; pBh += 32; pBl += 32;
  }

  // Epilogue: scores = acc*scale + mask_filled^T.
  if (maskT) {
#pragma unroll
    for (int mi = 0; mi < 8; ++mi) {
#pragma unroll
      for (int ni = 0; ni < 4; ++ni) {
        long row0q = bm + wr * 128 + mi * 16 + g * 4;
        long col = bn + wc * 64 + ni * 16 + r;
#pragma unroll
        for (int q = 0; q < 4; ++q) {
          long row = row0q + q;
          float mv = bf2f(maskT[row * (long)S_LEN + col]);
          C[row * (long)ldc + col] = acc[mi][ni][q] * scale + mv;
        }
      }
    }
  } else {
#pragma unroll
    for (int mi = 0; mi < 8; ++mi) {
#pragma unroll
      for (int ni = 0; ni < 4; ++ni) {
        long row0q = bm + wr * 128 + mi * 16 + g * 4;
        long col = bn + wc * 64 + ni * 16 + r;
#pragma unroll
        for (int q = 0; q < 4; ++q) {
          long row = row0q + q;
          float mv = mask[col * (long)S_LEN + row];
          float v = acc[mi][ni][q] * scale;
          v = (mv == 0.0f) ? -__builtin_inff() : (v + mv);
          C[row * (long)ldc + col] = v;
        }
      }
    }
  }
}

// ---------------------------------------------------------------------------
// Row softmax, IN PLACE (round-13-proven): reads 4096 fp32 of row blockIdx.x,
// writes 4096 bf16 into the first half of the same row (row stride 8192 ushorts).
__launch_bounds__(256)
__global__ void softmax_rows(float* __restrict__ Sc) {
  const long row = blockIdx.x;
  float* sr = Sc + row * (long)S_LEN;
  unsigned short* pr = (unsigned short*)sr;
  const int t = threadIdx.x;
  const int lane = t & 63, wid = t >> 6;

  float4 x[4];
  float m = -3.0e38f;
#pragma unroll
  for (int i = 0; i < 4; ++i) {
    x[i] = reinterpret_cast<const float4*>(sr)[t + i * 256];
    m = fmaxf(m, fmaxf(fmaxf(x[i].x, x[i].y), fmaxf(x[i].z, x[i].w)));
  }
#pragma unroll
  for (int o = 32; o; o >>= 1) m = fmaxf(m, __shfl_xor(m, o));
  __shared__ float redm[4];
  __shared__ float reds[4];
  if (lane == 0) redm[wid] = m;
  __syncthreads();
  m = fmaxf(fmaxf(redm[0], redm[1]), fmaxf(redm[2], redm[3]));

  float e[16];
  float s = 0.f;
#pragma unroll
  for (int i = 0; i < 4; ++i) {
    e[i * 4 + 0] = __expf(x[i].x - m);
    e[i * 4 + 1] = __expf(x[i].y - m);
    e[i * 4 + 2] = __expf(x[i].z - m);
    e[i * 4 + 3] = __expf(x[i].w - m);
    s += e[i * 4 + 0] + e[i * 4 + 1] + e[i * 4 + 2] + e[i * 4 + 3];
  }
#pragma unroll
  for (int o = 32; o; o >>= 1) s += __shfl_xor(s, o);
  if (lane == 0) reds[wid] = s;
  __syncthreads();
  s = reds[0] + reds[1] + reds[2] + reds[3];
  float inv = 1.0f / s;
#pragma unroll
  for (int i = 0; i < 4; ++i) {
    ushort4 o4;
    o4.x = f2bf(e[i * 4 + 0] * inv);
    o4.y = f2bf(e[i * 4 + 1] * inv);
    o4.z = f2bf(e[i * 4 + 2] * inv);
    o4.w = f2bf(e[i * 4 + 3] * inv);
    reinterpret_cast<ushort4*>(pr)[t + i * 256] = o4;
  }
}

// ---------------------------------------------------------------------------
extern "C" void kernel_launch(void* const* d_in, const int* in_sizes, int n_in,
                              void* d_out, int out_size, void* d_ws, size_t ws_size,
                              hipStream_t stream) {
  const float* emb  = (const float*)d_in[0];
  const float* mask = (const float*)d_in[1];
  const float* wq   = (const float*)d_in[2];
  const float* wk   = (const float*)d_in[3];
  const float* wv   = (const float*)d_in[4];
  float* out = (float*)d_out;
  char* ws = (char*)d_ws;

  // Workspace: rounds 4-13 layout (106,954,752, proven) plus optional maskT
  // [4096][4096] bf16 (need2 = 140,509,184; proven rounds 9-13).
  const size_t need = 106954752;
  const size_t need2 = need + (size_t)S_LEN * S_LEN * 2;
  if (ws_size < need) return;
  const bool useT = (ws_size >= need2);

  unsigned short* Eh  = (unsigned short*)(ws);
  unsigned short* El  = (unsigned short*)(ws + 8388608);
  unsigned short* QMh = (unsigned short*)(ws + 16777216);
  unsigned short* QMl = (unsigned short*)(ws + 25165824);
  unsigned short* Vt  = QMh;  // alias, live only after scores
  unsigned short* MtH = (unsigned short*)(ws + 33554432);
  unsigned short* MtL = (unsigned short*)(ws + 35651584);
  unsigned short* Wvt = (unsigned short*)(ws + 37748736);
  float* scores       = (float*)(ws + 39845888);
  unsigned short* WqH = (unsigned short*)(ws + 39845888);
  unsigned short* WqL = (unsigned short*)(ws + 39845888 + 2097152);
  unsigned short* WkH = (unsigned short*)(ws + 39845888 + 4194304);
  unsigned short* WkL = (unsigned short*)(ws + 39845888 + 6291456);
  unsigned short* maskT = useT ? (unsigned short*)(ws + need) : nullptr;

  // ---- once: split weights (merged), transpose Wv (+mask), precompute Mt --
  splitW<<<2048, 256, 0, stream>>>(wq, wk, WqH, WqL, WkH, WkL);
  prep_wv<<<dim3(32, 32), dim3(32, 8), 0, stream>>>(wv, Wvt);
  if (useT)
    prep_maskT<<<dim3(128, 128), dim3(32, 8), 0, stream>>>(mask, maskT);
  // Mt[d'][d] = sum_e Wk[d'][e]*Wq[d][e]: SPLIT, BM=64, KU=2 (grid 128).
  gemm_bt<1, 0, 2, 64><<<dim3(16, 8), 256, 0, stream>>>(
      WkH, WkL, 1024, WqH, WqL, 1024, (void*)MtH, 1024, MtL, 32);

  for (int b = 0; b < 2; ++b) {
    const float* embb = emb + (size_t)b * 4096 * 1024;
    float* outb = out + (size_t)b * 4096 * 1024;

    // 1) split embeddings into bf16 hi/lo
    split32<<<4096, 256, 0, stream>>>(embb, Eh, El);
    // 2) QM = E*Mt^T (SPLIT, BM=64, KU=2 -> grid 512, 48KB LDS), hi/lo store
    gemm_bt<1, 0, 2, 64><<<dim3(64, 8), 256, 0, stream>>>(
        Eh, El, 1024, MtH, MtL, 1024, (void*)QMh, 1024, QMl, 32);
    // 3) scores = (QM * E^T)/32 + mask_filled^T  (256^2 8-wave engine)
    gemm8s<<<dim3(16, 16), 512, 0, stream>>>(
        QMh, QMl, 1024, Eh, El, 1024, scores, 4096, mask, maskT, 0.03125f, 32);
    // 4) Vt = Wvt * E^T (plain bf16, BK=64, BM=64 -> grid 512)
    gemm_bt<0, 2, 2, 64><<<dim3(16, 32), 256, 0, stream>>>(
        Wvt, nullptr, 1024, Eh, nullptr, 1024, (void*)Vt, 4096, nullptr, 32);
    // 5) row softmax -> P bf16, IN PLACE over scores rows (stride 8192 ushorts)
    softmax_rows<<<4096, 256, 0, stream>>>(scores);
    // 6) out = P @ V (plain, BK=64, BM=64 -> grid 512), fp32 store
    gemm_bt<0, 3, 2, 64><<<dim3(64, 8), 256, 0, stream>>>(
        (unsigned short*)scores, nullptr, 8192, Vt, nullptr, 4096,
        (void*)outb, 1024, nullptr, 128);
  }
}